// Round 8
// baseline (766.870 us; speedup 1.0000x reference)
//
#include <hip/hip_runtime.h>
#include <hip/hip_bf16.h>
#include <float.h>

#define IN_DIM 128
#define EDGE_DIM 32
#define HID 64

// ---------------- K0: zero counters/stats + detect edge_index word stride ----------------
__global__ void k_init(int* cnt_col, int* cnt_row, float* stats, int* sflag,
                       const int* ei32, int N) {
    int i = blockIdx.x * blockDim.x + threadIdx.x;
    int stride = gridDim.x * blockDim.x;
    if (i == 0) {
        int odd_or = ei32[1] | ei32[3] | ei32[5] | ei32[7] | ei32[9] | ei32[11];
        sflag[0] = (odd_or == 0) ? 2 : 1;   // int64 -> stride 2 words, int32 -> 1
    }
    for (int j = i; j < N; j += stride) { cnt_col[j] = 0; cnt_row[j] = 0; }
    for (int j = i; j < 512; j += stride) stats[j] = 0.0f;
}

// ---------------- K1: u = W_src@a, v = W_dest@a, w = W_edge@a (wave per output) ----------------
__global__ void k_uvw(const float* __restrict__ Wsrc, const float* __restrict__ Wdst,
                      const float* __restrict__ Wedge, const float* __restrict__ avec,
                      float* u, float* v, float* w) {
    int wave = (blockIdx.x * blockDim.x + threadIdx.x) >> 6;
    int lane = threadIdx.x & 63;
    const float* src; float* dst; int row;
    if (wave < 128)      { src = Wsrc;  dst = u; row = wave; }
    else if (wave < 256) { src = Wdst;  dst = v; row = wave - 128; }
    else if (wave < 288) { src = Wedge; dst = w; row = wave - 256; }
    else return;
    float acc = src[row * HID + lane] * avec[lane];
    for (int o = 32; o >= 1; o >>= 1) acc += __shfl_xor(acc, o);
    if (lane == 0) dst[row] = acc;
}

// ---------------- K2: p[n] = x[n].u, q[n] = x[n].v (one wave per node) ----------------
__global__ void k_pq(const float* __restrict__ x, const float* __restrict__ u,
                     const float* __restrict__ v, float* p, float* q, int N) {
    int wave = (blockIdx.x * blockDim.x + threadIdx.x) >> 6;
    int lane = threadIdx.x & 63;
    if (wave >= N) return;
    const float* xr = x + (size_t)wave * IN_DIM;
    float a0 = xr[lane], a1 = xr[lane + 64];
    float pp = a0 * u[lane] + a1 * u[lane + 64];
    float qq = a0 * v[lane] + a1 * v[lane + 64];
    for (int m = 32; m >= 1; m >>= 1) { pp += __shfl_xor(pp, m); qq += __shfl_xor(qq, m); }
    if (lane == 0) { p[wave] = pp; q[wave] = qq; }
}

// ---------------- K3: scores + degree histograms (32 lanes per edge) ----------------
__global__ void k_escore(const float* __restrict__ ea, const int* __restrict__ ei,
                         const int* __restrict__ sflag,
                         const float* __restrict__ w, const float* __restrict__ p,
                         const float* __restrict__ q, float* scores,
                         int* cnt_col, int* cnt_row, int E) {
    int gid = blockIdx.x * blockDim.x + threadIdx.x;
    int e = gid >> 5;
    int j = gid & 31;
    if (e >= E) return;
    float val = ea[(size_t)e * EDGE_DIM + j] * w[j];
    for (int m = 16; m >= 1; m >>= 1) val += __shfl_xor(val, m);
    if (j == 0) {
        int s = sflag[0];
        int r = ei[(size_t)s * e];
        int c = ei[(size_t)s * (E + e)];
        atomicAdd(&cnt_col[c], 1);
        atomicAdd(&cnt_row[r], 1);
        float sc = val + p[r] + q[c];
        scores[e] = (sc > 0.f) ? sc : 0.2f * sc;
    }
}

// ---------------- K4: exclusive prefix scan (block 0: col, block 1: row) ----------------
__global__ __launch_bounds__(1024) void k_scan(const int* __restrict__ cnt_col,
                                               const int* __restrict__ cnt_row,
                                               int* start_col, int* cur_col,
                                               int* start_row, int* cur_row, int N) {
    const int* cnt = blockIdx.x ? cnt_row : cnt_col;
    int* start = blockIdx.x ? start_row : start_col;
    int* cur   = blockIdx.x ? cur_row   : cur_col;
    __shared__ int psum[1024];
    int t = threadIdx.x;
    int chunk = (N + 1023) / 1024;
    int lo = t * chunk, hi = min(lo + chunk, N);
    int s = 0;
    for (int i = lo; i < hi; i++) s += cnt[i];
    psum[t] = s;
    __syncthreads();
    for (int off = 1; off < 1024; off <<= 1) {
        int v = (t >= off) ? psum[t - off] : 0;
        __syncthreads();
        psum[t] += v;
        __syncthreads();
    }
    int run = (t == 0) ? 0 : psum[t - 1];
    for (int i = lo; i < hi; i++) {
        start[i] = run; cur[i] = run;
        run += cnt[i];
    }
    if (t == 1023) start[N] = psum[1023];
}

// ---------------- K5: place edge ids into per-node sorted lists ----------------
__global__ void k_place(const int* __restrict__ ei, const int* __restrict__ sflag,
                        int* cur_col, int* cur_row, int* idx_col, int* idx_row, int E) {
    int e = blockIdx.x * blockDim.x + threadIdx.x;
    if (e >= E) return;
    int s = sflag[0];
    int r = ei[(size_t)s * e];
    int c = ei[(size_t)s * (E + e)];
    int pc = atomicAdd(&cur_col[c], 1);
    idx_col[pc] = e;
    int pr = atomicAdd(&cur_row[r], 1);
    idx_row[pr] = e;
}

// ---------------- K6: per-col softmax stats + fwd max-reduce (wave per node) ----------------
__global__ __launch_bounds__(256) void k_fwd(const float* __restrict__ scores,
                                             const float* __restrict__ msg,
                                             const int* __restrict__ start_col,
                                             const int* __restrict__ idx_col,
                                             float* fwd, float* minv, float* sinv, int N) {
    int wave = (blockIdx.x * blockDim.x + threadIdx.x) >> 6;
    int lane = threadIdx.x & 63;
    if (wave >= N) return;
    int s0 = start_col[wave], s1 = start_col[wave + 1];
    int len = s1 - s0;
    if (len == 0) {
        fwd[(size_t)wave * HID + lane] = 0.f;
        if (lane == 0) { minv[wave] = 0.f; sinv[wave] = 0.f; }
        return;
    }
    // pass 1: segment softmax stats (lanes over edges)
    float m = -FLT_MAX;
    for (int i = lane; i < len; i += 64) m = fmaxf(m, scores[idx_col[s0 + i]]);
    for (int o = 32; o >= 1; o >>= 1) m = fmaxf(m, __shfl_xor(m, o));
    float ssum = 0.f;
    for (int i = lane; i < len; i += 64) ssum += expf(scores[idx_col[s0 + i]] - m);
    for (int o = 32; o >= 1; o >>= 1) ssum += __shfl_xor(ssum, o);
    float rcp = 1.f / ssum;
    if (lane == 0) { minv[wave] = m; sinv[wave] = rcp; }
    // pass 2: max over edges of msg*attn (lanes over h)
    float acc = -FLT_MAX;
    for (int i = 0; i < len; i++) {
        int e = idx_col[s0 + i];
        float attn = expf(scores[e] - m) * rcp;
        acc = fmaxf(acc, msg[(size_t)e * HID + lane] * attn);
    }
    fwd[(size_t)wave * HID + lane] = acc;
}

// ---------------- K7: bwd max-reduce over row lists (wave per node) ----------------
__global__ __launch_bounds__(256) void k_bwd(const float* __restrict__ scores,
                                             const float* __restrict__ msg,
                                             const int* __restrict__ start_row,
                                             const int* __restrict__ idx_row,
                                             const int* __restrict__ ei,
                                             const int* __restrict__ sflag,
                                             const float* __restrict__ minv,
                                             const float* __restrict__ sinv,
                                             float* bwd, int N, int E) {
    int wave = (blockIdx.x * blockDim.x + threadIdx.x) >> 6;
    int lane = threadIdx.x & 63;
    if (wave >= N) return;
    int s0 = start_row[wave], s1 = start_row[wave + 1];
    int len = s1 - s0;
    int s = sflag[0];
    float acc = -FLT_MAX;
    for (int i = 0; i < len; i++) {
        int e = idx_row[s0 + i];
        int c = ei[(size_t)s * (E + e)];
        float attn = expf(scores[e] - minv[c]) * sinv[c];
        acc = fmaxf(acc, msg[(size_t)e * HID + lane] * attn);
    }
    bwd[(size_t)wave * HID + lane] = (len > 0) ? acc : 0.f;
}

// ---------------- K8: pre1[n,h] = b1[h] + sum_k cat(fwd,bwd)[n,k]*W1[k,h] ----------------
__global__ void k_mlp1(const float* __restrict__ fwd, const float* __restrict__ bwd,
                       const float* __restrict__ W1, const float* __restrict__ b1,
                       float* pre1, int N) {
    int gid = blockIdx.x * blockDim.x + threadIdx.x;
    int n = gid >> 6, h = gid & 63;
    if (n >= N) return;
    const float* fr = fwd + (size_t)n * HID;
    const float* br = bwd + (size_t)n * HID;
    float acc = b1[h];
    for (int k = 0; k < HID; k++) acc += fr[k] * W1[k * HID + h];
    for (int k = 0; k < HID; k++) acc += br[k] * W1[(HID + k) * HID + h];
    pre1[(size_t)n * HID + h] = acc;
}

// ---------------- K9: per-feature sum / sum-sq over rows ----------------
__global__ __launch_bounds__(256) void k_stats(const float* __restrict__ pre,
                                               float* gsum, float* gss, int N) {
    __shared__ float lsum[HID], lss[HID];
    int t = threadIdx.x;
    if (t < HID) { lsum[t] = 0.f; lss[t] = 0.f; }
    __syncthreads();
    int h = t & 63, lr = t >> 6;
    float s = 0.f, ss = 0.f;
    for (int n = blockIdx.x * 4 + lr; n < N; n += gridDim.x * 4) {
        float vv = pre[(size_t)n * HID + h];
        s += vv; ss += vv * vv;
    }
    atomicAdd(&lsum[h], s);
    atomicAdd(&lss[h], ss);
    __syncthreads();
    if (t < HID) { atomicAdd(&gsum[t], lsum[t]); atomicAdd(&gss[t], lss[t]); }
}

// ---------------- K10: finalize BN -> scale/shift ----------------
__global__ void k_bnfin(const float* __restrict__ gsum, const float* __restrict__ gss,
                        const float* __restrict__ g, const float* __restrict__ b,
                        float* scale, float* shift, int N) {
    int t = threadIdx.x;
    if (t >= HID) return;
    float invN = 1.0f / (float)N;
    float mu = gsum[t] * invN;
    float var = gss[t] * invN - mu * mu;
    float rs = rsqrtf(var + 1e-5f);
    float sc = rs * g[t];
    scale[t] = sc;
    shift[t] = b[t] - mu * sc;
}

// ---------------- K11: pre2 = relu(bn1(pre1)) @ W2 + b2 ----------------
__global__ void k_mlp2(const float* __restrict__ pre1, const float* __restrict__ scale1,
                       const float* __restrict__ shift1,
                       const float* __restrict__ W2, const float* __restrict__ b2v,
                       float* pre2, int N) {
    int gid = blockIdx.x * blockDim.x + threadIdx.x;
    int n = gid >> 6, h = gid & 63;
    if (n >= N) return;
    const float* pr = pre1 + (size_t)n * HID;
    float acc = b2v[h];
    for (int k = 0; k < HID; k++) {
        float z = pr[k] * scale1[k] + shift1[k];
        z = (z > 0.f) ? z : 0.f;
        acc += z * W2[k * HID + h];
    }
    pre2[(size_t)n * HID + h] = acc;
}

// ---------------- K12: h2 = relu(bn2(pre2)); gate = sigmoid(h2@amw+amb); f32 out ----------------
__global__ void k_out(const float* __restrict__ pre2, const float* __restrict__ scale2,
                      const float* __restrict__ shift2, const float* __restrict__ amw,
                      const float* __restrict__ amb, float* out, int N) {
    int gid = blockIdx.x * blockDim.x + threadIdx.x;
    int n = gid >> 6, h = gid & 63;
    if (n >= N) return;
    float z = pre2[(size_t)n * HID + h] * scale2[h] + shift2[h];
    float h2 = (z > 0.f) ? z : 0.f;
    out[(size_t)n * HID + h] = h2;
    float part = h2 * amw[h];
    for (int m = 32; m >= 1; m >>= 1) part += __shfl_xor(part, m);
    if (h == 0) {
        float gate = 1.0f / (1.0f + expf(-(part + amb[0])));
        out[(size_t)N * HID + n] = gate;
    }
}

extern "C" void kernel_launch(void* const* d_in, const int* in_sizes, int n_in,
                              void* d_out, int out_size, void* d_ws, size_t ws_size,
                              hipStream_t stream) {
    const float* x     = (const float*)d_in[0];
    const int*   ei    = (const int*)d_in[1];
    const float* ea    = (const float*)d_in[2];
    const float* msg   = (const float*)d_in[3];
    const float* Wsrc  = (const float*)d_in[4];
    const float* Wdst  = (const float*)d_in[5];
    const float* Wedge = (const float*)d_in[6];
    const float* avec  = (const float*)d_in[7];
    const float* W1    = (const float*)d_in[8];
    const float* b1    = (const float*)d_in[9];
    const float* g1    = (const float*)d_in[10];
    const float* bb1   = (const float*)d_in[11];
    const float* W2    = (const float*)d_in[12];
    const float* b2    = (const float*)d_in[13];
    const float* g2    = (const float*)d_in[14];
    const float* bb2   = (const float*)d_in[15];
    const float* amw   = (const float*)d_in[16];
    const float* amb   = (const float*)d_in[17];
    float* out = (float*)d_out;   // reference output dtype is float32

    const int N = in_sizes[0] / IN_DIM;   // 50000
    const int E = in_sizes[1] / 2;        // 800000
    const int NH = N * HID;

    // ---- workspace: [hdr 1024][T = transient 3.2M][fwd NH][bwd NH] = 38.4 MB ----
    float* ws = (float*)d_ws;
    // hdr
    float* gsum1  = ws;         // 64
    float* gss1   = ws + 64;
    float* gsum2  = ws + 128;
    float* gss2   = ws + 192;
    float* scale1 = ws + 256;
    float* shift1 = ws + 320;
    float* scale2 = ws + 384;
    float* shift2 = ws + 448;
    int*   sflag  = (int*)(ws + 512);
    float* u      = ws + 576;   // 128
    float* v      = ws + 704;   // 128
    float* w      = ws + 832;   // 32
    // transient block T (dead before k_mlp1; pre1 overlays it)
    float* T        = ws + 1024;
    float* p        = T;                       // N
    float* q        = p + N;                   // N
    float* scores   = q + N;                   // E
    float* minv     = scores + E;              // N
    float* sinv     = minv + N;                // N
    int*   cnt_col  = (int*)(sinv + N);        // N
    int*   cnt_row  = cnt_col + N;             // N
    int*   start_col= cnt_row + N;             // N+1
    int*   start_row= start_col + N + 1;       // N+1
    int*   cur_col  = start_row + N + 1;       // N
    int*   cur_row  = cur_col + N;             // N
    int*   idx_col  = cur_row + N;             // E
    int*   idx_row  = idx_col + E;             // E   (total 8N+3E+2 = 2.8M <= NH)
    // persistent
    float* fwd  = ws + 1024 + (size_t)NH;      // NH
    float* bwd  = fwd + (size_t)NH;            // NH
    float* pre1 = T;                           // overlay transients (dead)
    float* pre2 = fwd;                         // overlay fwd (dead after mlp1)

    hipLaunchKernelGGL(k_init, dim3(256), dim3(256), 0, stream,
                       cnt_col, cnt_row, gsum1, sflag, ei, N);
    hipLaunchKernelGGL(k_uvw, dim3(72), dim3(256), 0, stream,
                       Wsrc, Wdst, Wedge, avec, u, v, w);
    hipLaunchKernelGGL(k_pq, dim3((N * 64 + 255) / 256), dim3(256), 0, stream,
                       x, u, v, p, q, N);
    hipLaunchKernelGGL(k_escore, dim3((E * 32 + 255) / 256), dim3(256), 0, stream,
                       ea, ei, sflag, w, p, q, scores, cnt_col, cnt_row, E);
    hipLaunchKernelGGL(k_scan, dim3(2), dim3(1024), 0, stream,
                       cnt_col, cnt_row, start_col, cur_col, start_row, cur_row, N);
    hipLaunchKernelGGL(k_place, dim3((E + 255) / 256), dim3(256), 0, stream,
                       ei, sflag, cur_col, cur_row, idx_col, idx_row, E);
    hipLaunchKernelGGL(k_fwd, dim3((N + 3) / 4), dim3(256), 0, stream,
                       scores, msg, start_col, idx_col, fwd, minv, sinv, N);
    hipLaunchKernelGGL(k_bwd, dim3((N + 3) / 4), dim3(256), 0, stream,
                       scores, msg, start_row, idx_row, ei, sflag, minv, sinv, bwd, N, E);
    hipLaunchKernelGGL(k_mlp1, dim3((N * 64 + 255) / 256), dim3(256), 0, stream,
                       fwd, bwd, W1, b1, pre1, N);
    hipLaunchKernelGGL(k_stats, dim3(1024), dim3(256), 0, stream,
                       pre1, gsum1, gss1, N);
    hipLaunchKernelGGL(k_bnfin, dim3(1), dim3(64), 0, stream,
                       gsum1, gss1, g1, bb1, scale1, shift1, N);
    hipLaunchKernelGGL(k_mlp2, dim3((N * 64 + 255) / 256), dim3(256), 0, stream,
                       pre1, scale1, shift1, W2, b2, pre2, N);
    hipLaunchKernelGGL(k_stats, dim3(1024), dim3(256), 0, stream,
                       pre2, gsum2, gss2, N);
    hipLaunchKernelGGL(k_bnfin, dim3(1), dim3(64), 0, stream,
                       gsum2, gss2, g2, bb2, scale2, shift2, N);
    hipLaunchKernelGGL(k_out, dim3((N * 64 + 255) / 256), dim3(256), 0, stream,
                       pre2, scale2, shift2, amw, amb, out, N);
}

// Round 9
// 683.326 us; speedup vs baseline: 1.1223x; 1.1223x over previous
//
#include <hip/hip_runtime.h>
#include <hip/hip_bf16.h>
#include <float.h>

#define IN_DIM 128
#define EDGE_DIM 32
#define HID 64

// ---------------- K0b: detect edge_index stride + degree histograms ----------------
__global__ void k_hist(const int* __restrict__ ei32, int* sflag,
                       int* cnt_col, int* cnt_row, int E) {
    int i = blockIdx.x * blockDim.x + threadIdx.x;
    int stride = gridDim.x * blockDim.x;
    int odd_or = ei32[1] | ei32[3] | ei32[5] | ei32[7] | ei32[9] | ei32[11];
    int s = (odd_or == 0) ? 2 : 1;     // int64 -> 2 words/elem, int32 -> 1
    if (i == 0) sflag[0] = s;
    for (int e = i; e < E; e += stride) {
        atomicAdd(&cnt_row[ei32[(size_t)s * e]], 1);
        atomicAdd(&cnt_col[ei32[(size_t)s * (E + e)]], 1);
    }
}

// ---------------- K1: u = W_src@a, v = W_dest@a, w = W_edge@a (wave per output) ----------------
__global__ void k_uvw(const float* __restrict__ Wsrc, const float* __restrict__ Wdst,
                      const float* __restrict__ Wedge, const float* __restrict__ avec,
                      float* u, float* v, float* w) {
    int wave = (blockIdx.x * blockDim.x + threadIdx.x) >> 6;
    int lane = threadIdx.x & 63;
    const float* src; float* dst; int row;
    if (wave < 128)      { src = Wsrc;  dst = u; row = wave; }
    else if (wave < 256) { src = Wdst;  dst = v; row = wave - 128; }
    else if (wave < 288) { src = Wedge; dst = w; row = wave - 256; }
    else return;
    float acc = src[row * HID + lane] * avec[lane];
    for (int o = 32; o >= 1; o >>= 1) acc += __shfl_xor(acc, o);
    if (lane == 0) dst[row] = acc;
}

// ---------------- K2: p[n] = x[n].u, q[n] = x[n].v (one wave per node) ----------------
__global__ void k_pq(const float* __restrict__ x, const float* __restrict__ u,
                     const float* __restrict__ v, float* p, float* q, int N) {
    int wave = (blockIdx.x * blockDim.x + threadIdx.x) >> 6;
    int lane = threadIdx.x & 63;
    if (wave >= N) return;
    const float* xr = x + (size_t)wave * IN_DIM;
    float a0 = xr[lane], a1 = xr[lane + 64];
    float pp = a0 * u[lane] + a1 * u[lane + 64];
    float qq = a0 * v[lane] + a1 * v[lane + 64];
    for (int m = 32; m >= 1; m >>= 1) { pp += __shfl_xor(pp, m); qq += __shfl_xor(qq, m); }
    if (lane == 0) { p[wave] = pp; q[wave] = qq; }
}

// ---------------- K3: scores (8 lanes/edge, float4) ----------------
__global__ void k_escore(const float* __restrict__ ea, const int* __restrict__ ei,
                         const int* __restrict__ sflag,
                         const float* __restrict__ w, const float* __restrict__ p,
                         const float* __restrict__ q, float* scores, int E) {
    int gid = blockIdx.x * blockDim.x + threadIdx.x;
    int e = gid >> 3;
    int j = gid & 7;
    if (e >= E) return;
    float4 av = ((const float4*)ea)[(size_t)e * 8 + j];
    float4 wv = ((const float4*)w)[j];
    float val = av.x * wv.x + av.y * wv.y + av.z * wv.z + av.w * wv.w;
    val += __shfl_xor(val, 4);
    val += __shfl_xor(val, 2);
    val += __shfl_xor(val, 1);
    if (j == 0) {
        int s = sflag[0];
        int r = ei[(size_t)s * e];
        int c = ei[(size_t)s * (E + e)];
        float sc = val + p[r] + q[c];
        scores[e] = (sc > 0.f) ? sc : 0.2f * sc;
    }
}

// ---------------- K4: exclusive prefix scan (block 0: col, block 1: row) ----------------
__global__ __launch_bounds__(1024) void k_scan(const int* __restrict__ cnt_col,
                                               const int* __restrict__ cnt_row,
                                               int* start_col, int* cur_col,
                                               int* start_row, int* cur_row, int N) {
    const int* cnt = blockIdx.x ? cnt_row : cnt_col;
    int* start = blockIdx.x ? start_row : start_col;
    int* cur   = blockIdx.x ? cur_row   : cur_col;
    __shared__ int psum[1024];
    int t = threadIdx.x;
    int chunk = (N + 1023) / 1024;
    int lo = t * chunk, hi = min(lo + chunk, N);
    int s = 0;
    for (int i = lo; i < hi; i++) s += cnt[i];
    psum[t] = s;
    __syncthreads();
    for (int off = 1; off < 1024; off <<= 1) {
        int v = (t >= off) ? psum[t - off] : 0;
        __syncthreads();
        psum[t] += v;
        __syncthreads();
    }
    int run = (t == 0) ? 0 : psum[t - 1];
    for (int i = lo; i < hi; i++) {
        start[i] = run; cur[i] = run;
        run += cnt[i];
    }
    if (t == 1023) start[N] = psum[1023];
}

// ---------------- K5: place edge ids into per-node sorted lists ----------------
__global__ void k_place(const int* __restrict__ ei, const int* __restrict__ sflag,
                        int* cur_col, int* cur_row, int* idx_col, int* idx_row, int E) {
    int e = blockIdx.x * blockDim.x + threadIdx.x;
    if (e >= E) return;
    int s = sflag[0];
    int r = ei[(size_t)s * e];
    int c = ei[(size_t)s * (E + e)];
    int pc = atomicAdd(&cur_col[c], 1);
    idx_col[pc] = e;
    int pr = atomicAdd(&cur_row[r], 1);
    idx_row[pr] = e;
}

// ---------------- K6: softmax stats, attn write-back, fwd max (wave per col-node) ----------------
__global__ __launch_bounds__(256) void k_fwd(float* scores, const float* __restrict__ msg,
                                             const int* __restrict__ start_col,
                                             const int* __restrict__ idx_col,
                                             float* fwd, int N) {
    int wave = (blockIdx.x * blockDim.x + threadIdx.x) >> 6;
    int lane = threadIdx.x & 63;
    if (wave >= N) return;
    int s0 = start_col[wave], len = start_col[wave + 1] - s0;
    if (len == 0) { fwd[(size_t)wave * HID + lane] = 0.f; return; }
    // pass 1a: segment max (lanes over edges)
    float m = -FLT_MAX;
    for (int i = lane; i < len; i += 64) m = fmaxf(m, scores[idx_col[s0 + i]]);
    for (int o = 32; o >= 1; o >>= 1) m = fmaxf(m, __shfl_xor(m, o));
    // pass 1b: segment sum of exp
    float ssum = 0.f;
    for (int i = lane; i < len; i += 64) ssum += expf(scores[idx_col[s0 + i]] - m);
    for (int o = 32; o >= 1; o >>= 1) ssum += __shfl_xor(ssum, o);
    float rcp = 1.f / ssum;
    // pass 1c: write attn back into scores (each edge owned by exactly one col list)
    for (int i = lane; i < len; i += 64) {
        int e = idx_col[s0 + i];
        scores[e] = expf(scores[e] - m) * rcp;
    }
    // pass 2: max over edges of msg*attn (lanes over h), 4-way unrolled
    float acc = -FLT_MAX;
    int i = 0;
    for (; i + 4 <= len; i += 4) {
        int e0 = idx_col[s0 + i],     e1 = idx_col[s0 + i + 1];
        int e2 = idx_col[s0 + i + 2], e3 = idx_col[s0 + i + 3];
        float a0 = scores[e0], a1 = scores[e1], a2 = scores[e2], a3 = scores[e3];
        float v0 = msg[(size_t)e0 * HID + lane] * a0;
        float v1 = msg[(size_t)e1 * HID + lane] * a1;
        float v2 = msg[(size_t)e2 * HID + lane] * a2;
        float v3 = msg[(size_t)e3 * HID + lane] * a3;
        acc = fmaxf(acc, fmaxf(fmaxf(v0, v1), fmaxf(v2, v3)));
    }
    for (; i < len; i++) {
        int e = idx_col[s0 + i];
        acc = fmaxf(acc, msg[(size_t)e * HID + lane] * scores[e]);
    }
    fwd[(size_t)wave * HID + lane] = acc;
}

// ---------------- K7: bwd max over row lists using precomputed attn ----------------
__global__ __launch_bounds__(256) void k_bwd(const float* __restrict__ scores,
                                             const float* __restrict__ msg,
                                             const int* __restrict__ start_row,
                                             const int* __restrict__ idx_row,
                                             float* bwd, int N) {
    int wave = (blockIdx.x * blockDim.x + threadIdx.x) >> 6;
    int lane = threadIdx.x & 63;
    if (wave >= N) return;
    int s0 = start_row[wave], len = start_row[wave + 1] - s0;
    if (len == 0) { bwd[(size_t)wave * HID + lane] = 0.f; return; }
    float acc = -FLT_MAX;
    int i = 0;
    for (; i + 4 <= len; i += 4) {
        int e0 = idx_row[s0 + i],     e1 = idx_row[s0 + i + 1];
        int e2 = idx_row[s0 + i + 2], e3 = idx_row[s0 + i + 3];
        float a0 = scores[e0], a1 = scores[e1], a2 = scores[e2], a3 = scores[e3];
        float v0 = msg[(size_t)e0 * HID + lane] * a0;
        float v1 = msg[(size_t)e1 * HID + lane] * a1;
        float v2 = msg[(size_t)e2 * HID + lane] * a2;
        float v3 = msg[(size_t)e3 * HID + lane] * a3;
        acc = fmaxf(acc, fmaxf(fmaxf(v0, v1), fmaxf(v2, v3)));
    }
    for (; i < len; i++) {
        int e = idx_row[s0 + i];
        acc = fmaxf(acc, msg[(size_t)e * HID + lane] * scores[e]);
    }
    bwd[(size_t)wave * HID + lane] = acc;
}

// ---------------- K8: pre1[n,h] = b1[h] + sum_k cat(fwd,bwd)[n,k]*W1[k,h] ----------------
__global__ void k_mlp1(const float* __restrict__ fwd, const float* __restrict__ bwd,
                       const float* __restrict__ W1, const float* __restrict__ b1,
                       float* pre1, int N) {
    int gid = blockIdx.x * blockDim.x + threadIdx.x;
    int n = gid >> 6, h = gid & 63;
    if (n >= N) return;
    const float* fr = fwd + (size_t)n * HID;
    const float* br = bwd + (size_t)n * HID;
    float acc = b1[h];
    for (int k = 0; k < HID; k++) acc += fr[k] * W1[k * HID + h];
    for (int k = 0; k < HID; k++) acc += br[k] * W1[(HID + k) * HID + h];
    pre1[(size_t)n * HID + h] = acc;
}

// ---------------- K9: per-feature sum / sum-sq over rows ----------------
__global__ __launch_bounds__(256) void k_stats(const float* __restrict__ pre,
                                               float* gsum, float* gss, int N) {
    __shared__ float lsum[HID], lss[HID];
    int t = threadIdx.x;
    if (t < HID) { lsum[t] = 0.f; lss[t] = 0.f; }
    __syncthreads();
    int h = t & 63, lr = t >> 6;
    float s = 0.f, ss = 0.f;
    for (int n = blockIdx.x * 4 + lr; n < N; n += gridDim.x * 4) {
        float vv = pre[(size_t)n * HID + h];
        s += vv; ss += vv * vv;
    }
    atomicAdd(&lsum[h], s);
    atomicAdd(&lss[h], ss);
    __syncthreads();
    if (t < HID) { atomicAdd(&gsum[t], lsum[t]); atomicAdd(&gss[t], lss[t]); }
}

// ---------------- K10: finalize BN -> scale/shift ----------------
__global__ void k_bnfin(const float* __restrict__ gsum, const float* __restrict__ gss,
                        const float* __restrict__ g, const float* __restrict__ b,
                        float* scale, float* shift, int N) {
    int t = threadIdx.x;
    if (t >= HID) return;
    float invN = 1.0f / (float)N;
    float mu = gsum[t] * invN;
    float var = gss[t] * invN - mu * mu;
    float rs = rsqrtf(var + 1e-5f);
    float sc = rs * g[t];
    scale[t] = sc;
    shift[t] = b[t] - mu * sc;
}

// ---------------- K11: pre2 = relu(bn1(pre1)) @ W2 + b2 ----------------
__global__ void k_mlp2(const float* __restrict__ pre1, const float* __restrict__ scale1,
                       const float* __restrict__ shift1,
                       const float* __restrict__ W2, const float* __restrict__ b2v,
                       float* pre2, int N) {
    int gid = blockIdx.x * blockDim.x + threadIdx.x;
    int n = gid >> 6, h = gid & 63;
    if (n >= N) return;
    const float* pr = pre1 + (size_t)n * HID;
    float acc = b2v[h];
    for (int k = 0; k < HID; k++) {
        float z = pr[k] * scale1[k] + shift1[k];
        z = (z > 0.f) ? z : 0.f;
        acc += z * W2[k * HID + h];
    }
    pre2[(size_t)n * HID + h] = acc;
}

// ---------------- K12: h2 = relu(bn2(pre2)); gate = sigmoid(h2@amw+amb); f32 out ----------------
__global__ void k_out(const float* __restrict__ pre2, const float* __restrict__ scale2,
                      const float* __restrict__ shift2, const float* __restrict__ amw,
                      const float* __restrict__ amb, float* out, int N) {
    int gid = blockIdx.x * blockDim.x + threadIdx.x;
    int n = gid >> 6, h = gid & 63;
    if (n >= N) return;
    float z = pre2[(size_t)n * HID + h] * scale2[h] + shift2[h];
    float h2 = (z > 0.f) ? z : 0.f;
    out[(size_t)n * HID + h] = h2;
    float part = h2 * amw[h];
    for (int m = 32; m >= 1; m >>= 1) part += __shfl_xor(part, m);
    if (h == 0) {
        float gate = 1.0f / (1.0f + expf(-(part + amb[0])));
        out[(size_t)N * HID + n] = gate;
    }
}

extern "C" void kernel_launch(void* const* d_in, const int* in_sizes, int n_in,
                              void* d_out, int out_size, void* d_ws, size_t ws_size,
                              hipStream_t stream) {
    const float* x     = (const float*)d_in[0];
    const int*   ei    = (const int*)d_in[1];
    const float* ea    = (const float*)d_in[2];
    const float* msg   = (const float*)d_in[3];
    const float* Wsrc  = (const float*)d_in[4];
    const float* Wdst  = (const float*)d_in[5];
    const float* Wedge = (const float*)d_in[6];
    const float* avec  = (const float*)d_in[7];
    const float* W1    = (const float*)d_in[8];
    const float* b1    = (const float*)d_in[9];
    const float* g1    = (const float*)d_in[10];
    const float* bb1   = (const float*)d_in[11];
    const float* W2    = (const float*)d_in[12];
    const float* b2    = (const float*)d_in[13];
    const float* g2    = (const float*)d_in[14];
    const float* bb2   = (const float*)d_in[15];
    const float* amw   = (const float*)d_in[16];
    const float* amb   = (const float*)d_in[17];
    float* out = (float*)d_out;   // reference output dtype is float32

    const int N = in_sizes[0] / IN_DIM;   // 50000
    const int E = in_sizes[1] / 2;        // 800000
    const int NH = N * HID;

    // ---- workspace: [hdr 1024][T transient / pre1 overlay NH][fwd NH][bwd NH] ----
    float* ws = (float*)d_ws;
    float* gsum1  = ws;         // 64
    float* gss1   = ws + 64;
    float* gsum2  = ws + 128;
    float* gss2   = ws + 192;
    float* scale1 = ws + 256;
    float* shift1 = ws + 320;
    float* scale2 = ws + 384;
    float* shift2 = ws + 448;
    int*   sflag  = (int*)(ws + 512);
    float* u      = ws + 576;   // 128
    float* v      = ws + 704;   // 128
    float* w      = ws + 832;   // 32 (16B-aligned)
    float* T        = ws + 1024;
    float* p        = T;                       // N
    float* q        = p + N;                   // N
    float* scores   = q + N;                   // E (becomes attn after k_fwd)
    int*   cnt_col  = (int*)(scores + E);      // N   } contiguous pair for one memset
    int*   cnt_row  = cnt_col + N;             // N   }
    int*   start_col= cnt_row + N;             // N+1
    int*   start_row= start_col + N + 1;       // N+1
    int*   cur_col  = start_row + N + 1;       // N
    int*   cur_row  = cur_col + N;             // N
    int*   idx_col  = cur_row + N;             // E
    int*   idx_row  = idx_col + E;             // E   (total 8N+3E+2 < NH)
    float* fwd  = ws + 1024 + (size_t)NH;      // NH
    float* bwd  = fwd + (size_t)NH;            // NH
    float* pre1 = T;                           // overlay transients (dead)
    float* pre2 = fwd;                         // overlay fwd (dead after mlp1)

    hipMemsetAsync(cnt_col, 0, (size_t)2 * N * sizeof(int), stream);
    hipMemsetAsync(ws, 0, 512 * sizeof(float), stream);
    hipLaunchKernelGGL(k_hist, dim3(1024), dim3(256), 0, stream,
                       ei, sflag, cnt_col, cnt_row, E);
    hipLaunchKernelGGL(k_uvw, dim3(72), dim3(256), 0, stream,
                       Wsrc, Wdst, Wedge, avec, u, v, w);
    hipLaunchKernelGGL(k_pq, dim3((N * 64 + 255) / 256), dim3(256), 0, stream,
                       x, u, v, p, q, N);
    hipLaunchKernelGGL(k_escore, dim3((E * 8 + 255) / 256), dim3(256), 0, stream,
                       ea, ei, sflag, w, p, q, scores, E);
    hipLaunchKernelGGL(k_scan, dim3(2), dim3(1024), 0, stream,
                       cnt_col, cnt_row, start_col, cur_col, start_row, cur_row, N);
    hipLaunchKernelGGL(k_place, dim3((E + 255) / 256), dim3(256), 0, stream,
                       ei, sflag, cur_col, cur_row, idx_col, idx_row, E);
    hipLaunchKernelGGL(k_fwd, dim3((N + 3) / 4), dim3(256), 0, stream,
                       scores, msg, start_col, idx_col, fwd, N);
    hipLaunchKernelGGL(k_bwd, dim3((N + 3) / 4), dim3(256), 0, stream,
                       scores, msg, start_row, idx_row, bwd, N);
    hipLaunchKernelGGL(k_mlp1, dim3((N * 64 + 255) / 256), dim3(256), 0, stream,
                       fwd, bwd, W1, b1, pre1, N);
    hipLaunchKernelGGL(k_stats, dim3(1024), dim3(256), 0, stream,
                       pre1, gsum1, gss1, N);
    hipLaunchKernelGGL(k_bnfin, dim3(1), dim3(64), 0, stream,
                       gsum1, gss1, g1, bb1, scale1, shift1, N);
    hipLaunchKernelGGL(k_mlp2, dim3((N * 64 + 255) / 256), dim3(256), 0, stream,
                       pre1, scale1, shift1, W2, b2, pre2, N);
    hipLaunchKernelGGL(k_stats, dim3(1024), dim3(256), 0, stream,
                       pre2, gsum2, gss2, N);
    hipLaunchKernelGGL(k_bnfin, dim3(1), dim3(64), 0, stream,
                       gsum2, gss2, g2, bb2, scale2, shift2, N);
    hipLaunchKernelGGL(k_out, dim3((N * 64 + 255) / 256), dim3(256), 0, stream,
                       pre2, scale2, shift2, amw, amb, out, N);
}

// Round 11
// 475.141 us; speedup vs baseline: 1.6140x; 1.4382x over previous
//
#include <hip/hip_runtime.h>
#include <hip/hip_bf16.h>
#include <float.h>

#define IN_DIM 128
#define EDGE_DIM 32
#define HID 64
#define BKT_G 64          // nodes per bucket
#define NSUB 8            // sub-buckets (XCD-affinity via blockIdx&7)
#define CAP 384           // per-sub-bucket capacity (mean 128, sigma ~11 -> 23 sigma)

// ---------------- K1: u,v,w projections + edge_index stride detect ----------------
__global__ void k_uvw(const float* __restrict__ Wsrc, const float* __restrict__ Wdst,
                      const float* __restrict__ Wedge, const float* __restrict__ avec,
                      const int* __restrict__ ei32, int* sflag,
                      float* u, float* v, float* w) {
    if (blockIdx.x == 0 && threadIdx.x == 0) {
        int odd_or = ei32[1] | ei32[3] | ei32[5] | ei32[7] | ei32[9] | ei32[11];
        sflag[0] = (odd_or == 0) ? 2 : 1;   // int64 -> 2 words/elem, int32 -> 1
    }
    int wave = (blockIdx.x * blockDim.x + threadIdx.x) >> 6;
    int lane = threadIdx.x & 63;
    const float* src; float* dst; int row;
    if (wave < 128)      { src = Wsrc;  dst = u; row = wave; }
    else if (wave < 256) { src = Wdst;  dst = v; row = wave - 128; }
    else if (wave < 288) { src = Wedge; dst = w; row = wave - 256; }
    else return;
    float acc = src[row * HID + lane] * avec[lane];
    for (int o = 32; o >= 1; o >>= 1) acc += __shfl_xor(acc, o);
    if (lane == 0) dst[row] = acc;
}

// ---------------- K2: p[n] = x[n].u, q[n] = x[n].v (one wave per node) ----------------
__global__ void k_pq(const float* __restrict__ x, const float* __restrict__ u,
                     const float* __restrict__ v, float* p, float* q, int N) {
    int wave = (blockIdx.x * blockDim.x + threadIdx.x) >> 6;
    int lane = threadIdx.x & 63;
    if (wave >= N) return;
    const float* xr = x + (size_t)wave * IN_DIM;
    float a0 = xr[lane], a1 = xr[lane + 64];
    float pp = a0 * u[lane] + a1 * u[lane + 64];
    float qq = a0 * v[lane] + a1 * v[lane + 64];
    for (int m = 32; m >= 1; m >>= 1) { pp += __shfl_xor(pp, m); qq += __shfl_xor(qq, m); }
    if (lane == 0) { p[wave] = pp; q[wave] = qq; }
}

// ---------------- K3: scores (8 lanes/edge, float4) ----------------
__global__ void k_escore(const float* __restrict__ ea, const int* __restrict__ ei,
                         const int* __restrict__ sflag,
                         const float* __restrict__ w, const float* __restrict__ p,
                         const float* __restrict__ q, float* scores, int E) {
    int gid = blockIdx.x * blockDim.x + threadIdx.x;
    int e = gid >> 3;
    int j = gid & 7;
    if (e >= E) return;
    float4 av = ((const float4*)ea)[(size_t)e * 8 + j];
    float4 wv = ((const float4*)w)[j];
    float val = av.x * wv.x + av.y * wv.y + av.z * wv.z + av.w * wv.w;
    val += __shfl_xor(val, 4);
    val += __shfl_xor(val, 2);
    val += __shfl_xor(val, 1);
    if (j == 0) {
        int s = sflag[0];
        int r = ei[(size_t)s * e];
        int c = ei[(size_t)s * (E + e)];
        float sc = val + p[r] + q[c];
        scores[e] = (sc > 0.f) ? sc : 0.2f * sc;
    }
}

// ---------------- K4: bin edges into sub-buckets by node id ----------------
// side=0: key = col (ei[E+e]); side=1: key = row (ei[e])
__global__ void k_binA(const int* __restrict__ ei, const int* __restrict__ sflag,
                       int* bcur, unsigned* bbuf, int E, int side) {
    int e = blockIdx.x * blockDim.x + threadIdx.x;
    if (e >= E) return;
    int s = sflag[0];
    int key = side ? ei[(size_t)s * e] : ei[(size_t)s * (E + e)];
    int b = key >> 6;
    int sub = blockIdx.x & (NSUB - 1);
    int pos = atomicAdd(&bcur[b * NSUB + sub], 1);
    if (pos < CAP) bbuf[((size_t)b * NSUB + sub) * CAP + pos] = (unsigned)((e << 6) | (key & 63));
}

// ---------------- K5: per-bucket LDS sort + softmax + attn writeback + fwd max ----------------
__global__ __launch_bounds__(512) void k_sortfwd(float* scores, const float* __restrict__ msg,
                                                 const int* __restrict__ bcur,
                                                 const unsigned* __restrict__ bbuf,
                                                 float* fwd, int N) {
    __shared__ unsigned raw[NSUB * CAP];
    __shared__ float    sc[NSUB * CAP];
    __shared__ unsigned idx[NSUB * CAP];
    __shared__ int cnt[BKT_G], cur[BKT_G], sstart[BKT_G + 1];
    __shared__ int subo[NSUB + 1];
    int b = blockIdx.x, tid = threadIdx.x;
    if (tid == 0) {
        int off = 0;
        for (int s = 0; s < NSUB; s++) {
            subo[s] = off;
            int c = bcur[b * NSUB + s]; if (c > CAP) c = CAP;
            off += c;
        }
        subo[NSUB] = off;
    }
    if (tid < BKT_G) cnt[tid] = 0;
    __syncthreads();
    int M = subo[NSUB];
    for (int s = 0; s < NSUB; s++) {
        int base = subo[s], c = subo[s + 1] - base;
        const unsigned* src = bbuf + ((size_t)b * NSUB + s) * CAP;
        for (int i = tid; i < c; i += 512) raw[base + i] = src[i];
    }
    __syncthreads();
    for (int j = tid; j < M; j += 512) {
        unsigned r = raw[j];
        sc[j] = scores[r >> 6];
        atomicAdd(&cnt[r & 63], 1);
    }
    __syncthreads();
    if (tid < BKT_G) {           // wave 0: exclusive scan of 64 counters
        int val = cnt[tid];
        int inc = val;
        for (int off = 1; off < BKT_G; off <<= 1) {
            int o = __shfl_up(inc, off);
            if (tid >= off) inc += o;
        }
        sstart[tid + 1] = inc;
        if (tid == 0) sstart[0] = 0;
        cur[tid] = inc - val;
    }
    __syncthreads();
    for (int j = tid; j < M; j += 512) {
        int c = raw[j] & 63;
        int posn = atomicAdd(&cur[c], 1);
        idx[posn] = j;
    }
    __syncthreads();
    int wave = tid >> 6, lane = tid & 63;
    for (int n = wave; n < BKT_G; n += 8) {
        int node = b * BKT_G + n;
        if (node >= N) continue;
        int a0 = sstart[n], len = sstart[n + 1] - a0;
        if (len == 0) { fwd[(size_t)node * HID + lane] = 0.f; continue; }
        float m = -FLT_MAX;
        for (int k = lane; k < len; k += 64) m = fmaxf(m, sc[idx[a0 + k]]);
        for (int o = 32; o >= 1; o >>= 1) m = fmaxf(m, __shfl_xor(m, o));
        float ssum = 0.f;
        for (int k = lane; k < len; k += 64) ssum += expf(sc[idx[a0 + k]] - m);
        for (int o = 32; o >= 1; o >>= 1) ssum += __shfl_xor(ssum, o);
        float rcp = 1.f / ssum;
        for (int k = lane; k < len; k += 64) {         // attn writeback (global only)
            unsigned j = idx[a0 + k];
            scores[raw[j] >> 6] = expf(sc[j] - m) * rcp;
        }
        float acc = -FLT_MAX;                           // max over msg*attn, lanes = h
        int k = 0;
        for (; k + 4 <= len; k += 4) {
            unsigned j0 = idx[a0+k], j1 = idx[a0+k+1], j2 = idx[a0+k+2], j3 = idx[a0+k+3];
            float A0 = expf(sc[j0]-m)*rcp, A1 = expf(sc[j1]-m)*rcp;
            float A2 = expf(sc[j2]-m)*rcp, A3 = expf(sc[j3]-m)*rcp;
            float v0 = msg[(size_t)(raw[j0]>>6) * HID + lane] * A0;
            float v1 = msg[(size_t)(raw[j1]>>6) * HID + lane] * A1;
            float v2 = msg[(size_t)(raw[j2]>>6) * HID + lane] * A2;
            float v3 = msg[(size_t)(raw[j3]>>6) * HID + lane] * A3;
            acc = fmaxf(acc, fmaxf(fmaxf(v0, v1), fmaxf(v2, v3)));
        }
        for (; k < len; k++) {
            unsigned j = idx[a0 + k];
            acc = fmaxf(acc, msg[(size_t)(raw[j]>>6) * HID + lane] * (expf(sc[j]-m)*rcp));
        }
        fwd[(size_t)node * HID + lane] = acc;
    }
}

// ---------------- K6: per-bucket LDS sort + bwd max (attn precomputed in scores) ----------------
__global__ __launch_bounds__(512) void k_sortbwd(const float* __restrict__ scores,
                                                 const float* __restrict__ msg,
                                                 const int* __restrict__ bcur,
                                                 const unsigned* __restrict__ bbuf,
                                                 float* bwd, int N) {
    __shared__ unsigned raw[NSUB * CAP];
    __shared__ float    sc[NSUB * CAP];
    __shared__ unsigned idx[NSUB * CAP];
    __shared__ int cnt[BKT_G], cur[BKT_G], sstart[BKT_G + 1];
    __shared__ int subo[NSUB + 1];
    int b = blockIdx.x, tid = threadIdx.x;
    if (tid == 0) {
        int off = 0;
        for (int s = 0; s < NSUB; s++) {
            subo[s] = off;
            int c = bcur[b * NSUB + s]; if (c > CAP) c = CAP;
            off += c;
        }
        subo[NSUB] = off;
    }
    if (tid < BKT_G) cnt[tid] = 0;
    __syncthreads();
    int M = subo[NSUB];
    for (int s = 0; s < NSUB; s++) {
        int base = subo[s], c = subo[s + 1] - base;
        const unsigned* src = bbuf + ((size_t)b * NSUB + s) * CAP;
        for (int i = tid; i < c; i += 512) raw[base + i] = src[i];
    }
    __syncthreads();
    for (int j = tid; j < M; j += 512) {
        unsigned r = raw[j];
        sc[j] = scores[r >> 6];         // attn
        atomicAdd(&cnt[r & 63], 1);
    }
    __syncthreads();
    if (tid < BKT_G) {
        int val = cnt[tid];
        int inc = val;
        for (int off = 1; off < BKT_G; off <<= 1) {
            int o = __shfl_up(inc, off);
            if (tid >= off) inc += o;
        }
        sstart[tid + 1] = inc;
        if (tid == 0) sstart[0] = 0;
        cur[tid] = inc - val;
    }
    __syncthreads();
    for (int j = tid; j < M; j += 512) {
        int c = raw[j] & 63;
        int posn = atomicAdd(&cur[c], 1);
        idx[posn] = j;
    }
    __syncthreads();
    int wave = tid >> 6, lane = tid & 63;
    for (int n = wave; n < BKT_G; n += 8) {
        int node = b * BKT_G + n;
        if (node >= N) continue;
        int a0 = sstart[n], len = sstart[n + 1] - a0;
        if (len == 0) { bwd[(size_t)node * HID + lane] = 0.f; continue; }
        float acc = -FLT_MAX;
        int k = 0;
        for (; k + 4 <= len; k += 4) {
            unsigned j0 = idx[a0+k], j1 = idx[a0+k+1], j2 = idx[a0+k+2], j3 = idx[a0+k+3];
            float v0 = msg[(size_t)(raw[j0]>>6) * HID + lane] * sc[j0];
            float v1 = msg[(size_t)(raw[j1]>>6) * HID + lane] * sc[j1];
            float v2 = msg[(size_t)(raw[j2]>>6) * HID + lane] * sc[j2];
            float v3 = msg[(size_t)(raw[j3]>>6) * HID + lane] * sc[j3];
            acc = fmaxf(acc, fmaxf(fmaxf(v0, v1), fmaxf(v2, v3)));
        }
        for (; k < len; k++) {
            unsigned j = idx[a0 + k];
            acc = fmaxf(acc, msg[(size_t)(raw[j]>>6) * HID + lane] * sc[j]);
        }
        bwd[(size_t)node * HID + lane] = acc;
    }
}

// ---------------- K7: pre1[n,h] = b1[h] + sum_k cat(fwd,bwd)[n,k]*W1[k,h] ----------------
__global__ void k_mlp1(const float* __restrict__ fwd, const float* __restrict__ bwd,
                       const float* __restrict__ W1, const float* __restrict__ b1,
                       float* pre1, int N) {
    int gid = blockIdx.x * blockDim.x + threadIdx.x;
    int n = gid >> 6, h = gid & 63;
    if (n >= N) return;
    const float* fr = fwd + (size_t)n * HID;
    const float* br = bwd + (size_t)n * HID;
    float acc = b1[h];
    for (int k = 0; k < HID; k++) acc += fr[k] * W1[k * HID + h];
    for (int k = 0; k < HID; k++) acc += br[k] * W1[(HID + k) * HID + h];
    pre1[(size_t)n * HID + h] = acc;
}

// ---------------- K8: per-feature sum / sum-sq over rows ----------------
__global__ __launch_bounds__(256) void k_stats(const float* __restrict__ pre,
                                               float* gsum, float* gss, int N) {
    __shared__ float lsum[HID], lss[HID];
    int t = threadIdx.x;
    if (t < HID) { lsum[t] = 0.f; lss[t] = 0.f; }
    __syncthreads();
    int h = t & 63, lr = t >> 6;
    float s = 0.f, ss = 0.f;
    for (int n = blockIdx.x * 4 + lr; n < N; n += gridDim.x * 4) {
        float vv = pre[(size_t)n * HID + h];
        s += vv; ss += vv * vv;
    }
    atomicAdd(&lsum[h], s);
    atomicAdd(&lss[h], ss);
    __syncthreads();
    if (t < HID) { atomicAdd(&gsum[t], lsum[t]); atomicAdd(&gss[t], lss[t]); }
}

// ---------------- K9: finalize BN -> scale/shift ----------------
__global__ void k_bnfin(const float* __restrict__ gsum, const float* __restrict__ gss,
                        const float* __restrict__ g, const float* __restrict__ b,
                        float* scale, float* shift, int N) {
    int t = threadIdx.x;
    if (t >= HID) return;
    float invN = 1.0f / (float)N;
    float mu = gsum[t] * invN;
    float var = gss[t] * invN - mu * mu;
    float rs = rsqrtf(var + 1e-5f);
    float sc = rs * g[t];
    scale[t] = sc;
    shift[t] = b[t] - mu * sc;
}

// ---------------- K10: pre2 = relu(bn1(pre1)) @ W2 + b2 ----------------
__global__ void k_mlp2(const float* __restrict__ pre1, const float* __restrict__ scale1,
                       const float* __restrict__ shift1,
                       const float* __restrict__ W2, const float* __restrict__ b2v,
                       float* pre2, int N) {
    int gid = blockIdx.x * blockDim.x + threadIdx.x;
    int n = gid >> 6, h = gid & 63;
    if (n >= N) return;
    const float* pr = pre1 + (size_t)n * HID;
    float acc = b2v[h];
    for (int k = 0; k < HID; k++) {
        float z = pr[k] * scale1[k] + shift1[k];
        z = (z > 0.f) ? z : 0.f;
        acc += z * W2[k * HID + h];
    }
    pre2[(size_t)n * HID + h] = acc;
}

// ---------------- K11: h2 = relu(bn2(pre2)); gate = sigmoid(h2@amw+amb); f32 out ----------------
__global__ void k_out(const float* __restrict__ pre2, const float* __restrict__ scale2,
                      const float* __restrict__ shift2, const float* __restrict__ amw,
                      const float* __restrict__ amb, float* out, int N) {
    int gid = blockIdx.x * blockDim.x + threadIdx.x;
    int n = gid >> 6, h = gid & 63;
    if (n >= N) return;
    float z = pre2[(size_t)n * HID + h] * scale2[h] + shift2[h];
    float h2 = (z > 0.f) ? z : 0.f;
    out[(size_t)n * HID + h] = h2;
    float part = h2 * amw[h];
    for (int m = 32; m >= 1; m >>= 1) part += __shfl_xor(part, m);
    if (h == 0) {
        float gate = 1.0f / (1.0f + expf(-(part + amb[0])));
        out[(size_t)N * HID + n] = gate;
    }
}

extern "C" void kernel_launch(void* const* d_in, const int* in_sizes, int n_in,
                              void* d_out, int out_size, void* d_ws, size_t ws_size,
                              hipStream_t stream) {
    const float* x     = (const float*)d_in[0];
    const int*   ei    = (const int*)d_in[1];
    const float* ea    = (const float*)d_in[2];
    const float* msg   = (const float*)d_in[3];
    const float* Wsrc  = (const float*)d_in[4];
    const float* Wdst  = (const float*)d_in[5];
    const float* Wedge = (const float*)d_in[6];
    const float* avec  = (const float*)d_in[7];
    const float* W1    = (const float*)d_in[8];
    const float* b1    = (const float*)d_in[9];
    const float* g1    = (const float*)d_in[10];
    const float* bb1   = (const float*)d_in[11];
    const float* W2    = (const float*)d_in[12];
    const float* b2    = (const float*)d_in[13];
    const float* g2    = (const float*)d_in[14];
    const float* bb2   = (const float*)d_in[15];
    const float* amw   = (const float*)d_in[16];
    const float* amb   = (const float*)d_in[17];
    float* out = (float*)d_out;

    const int N = in_sizes[0] / IN_DIM;   // 50000
    const int E = in_sizes[1] / 2;        // 800000
    const int NH = N * HID;
    const int nbkt = (N + BKT_G - 1) / BKT_G;   // 782

    // ---- workspace ----
    float* ws = (float*)d_ws;
    float* gsum1  = ws;
    float* gss1   = ws + 64;
    float* gsum2  = ws + 128;
    float* gss2   = ws + 192;
    float* scale1 = ws + 256;
    float* shift1 = ws + 320;
    float* scale2 = ws + 384;
    float* shift2 = ws + 448;
    int*   sflag  = (int*)(ws + 512);
    float* u      = ws + 576;
    float* v      = ws + 704;
    float* w      = ws + 832;   // 16B-aligned
    float* T        = ws + 1024;
    float* p        = T;                               // N
    float* q        = p + N;                           // N
    float* scores   = q + N;                           // E (attn after sortfwd)
    int*   bcur_col = (int*)(scores + E);              // nbkt*NSUB
    int*   bcur_row = bcur_col + nbkt * NSUB;          // nbkt*NSUB
    unsigned* bbuf  = (unsigned*)(bcur_row + nbkt * NSUB);   // nbkt*NSUB*CAP (shared col/row)
    size_t T_words  = 2 * (size_t)N + E + 2 * (size_t)nbkt * NSUB
                    + (size_t)nbkt * NSUB * CAP;
    size_t T_sz     = (T_words < (size_t)NH) ? (size_t)NH : T_words;
    float* fwd  = ws + 1024 + T_sz;                    // NH
    float* bwd  = fwd + (size_t)NH;                    // NH
    float* pre1 = T;                                   // overlay transients (dead)
    float* pre2 = fwd;                                 // overlay fwd (dead after mlp1)

    (void)hipMemsetAsync(bcur_col, 0, (size_t)2 * nbkt * NSUB * sizeof(int), stream);
    (void)hipMemsetAsync(ws, 0, 512 * sizeof(float), stream);
    hipLaunchKernelGGL(k_uvw, dim3(72), dim3(256), 0, stream,
                       Wsrc, Wdst, Wedge, avec, ei, sflag, u, v, w);
    hipLaunchKernelGGL(k_pq, dim3((N * 64 + 255) / 256), dim3(256), 0, stream,
                       x, u, v, p, q, N);
    hipLaunchKernelGGL(k_escore, dim3((E * 8 + 255) / 256), dim3(256), 0, stream,
                       ea, ei, sflag, w, p, q, scores, E);
    hipLaunchKernelGGL(k_binA, dim3((E + 255) / 256), dim3(256), 0, stream,
                       ei, sflag, bcur_col, bbuf, E, 0);
    hipLaunchKernelGGL(k_sortfwd, dim3(nbkt), dim3(512), 0, stream,
                       scores, msg, bcur_col, bbuf, fwd, N);
    hipLaunchKernelGGL(k_binA, dim3((E + 255) / 256), dim3(256), 0, stream,
                       ei, sflag, bcur_row, bbuf, E, 1);
    hipLaunchKernelGGL(k_sortbwd, dim3(nbkt), dim3(512), 0, stream,
                       scores, msg, bcur_row, bbuf, bwd, N);
    hipLaunchKernelGGL(k_mlp1, dim3((N * 64 + 255) / 256), dim3(256), 0, stream,
                       fwd, bwd, W1, b1, pre1, N);
    hipLaunchKernelGGL(k_stats, dim3(1024), dim3(256), 0, stream,
                       pre1, gsum1, gss1, N);
    hipLaunchKernelGGL(k_bnfin, dim3(1), dim3(64), 0, stream,
                       gsum1, gss1, g1, bb1, scale1, shift1, N);
    hipLaunchKernelGGL(k_mlp2, dim3((N * 64 + 255) / 256), dim3(256), 0, stream,
                       pre1, scale1, shift1, W2, b2, pre2, N);
    hipLaunchKernelGGL(k_stats, dim3(1024), dim3(256), 0, stream,
                       pre2, gsum2, gss2, N);
    hipLaunchKernelGGL(k_bnfin, dim3(1), dim3(64), 0, stream,
                       gsum2, gss2, g2, bb2, scale2, shift2, N);
    hipLaunchKernelGGL(k_out, dim3((N * 64 + 255) / 256), dim3(256), 0, stream,
                       pre2, scale2, shift2, amw, amb, out, N);
}

// Round 12
// 429.777 us; speedup vs baseline: 1.7843x; 1.1056x over previous
//
#include <hip/hip_runtime.h>
#include <hip/hip_bf16.h>
#include <float.h>

#define IN_DIM 128
#define EDGE_DIM 32
#define HID 64
#define BKT_G 64          // nodes per bucket
#define NSUB 8            // sub-buckets (XCD-affinity via blockIdx&7)
#define CAP 384           // per-sub-bucket capacity

// ---------------- K1: u,v,w projections + edge_index stride detect ----------------
__global__ void k_uvw(const float* __restrict__ Wsrc, const float* __restrict__ Wdst,
                      const float* __restrict__ Wedge, const float* __restrict__ avec,
                      const int* __restrict__ ei32, int* sflag,
                      float* u, float* v, float* w) {
    if (blockIdx.x == 0 && threadIdx.x == 0) {
        int odd_or = ei32[1] | ei32[3] | ei32[5] | ei32[7] | ei32[9] | ei32[11];
        sflag[0] = (odd_or == 0) ? 2 : 1;   // int64 -> 2 words/elem, int32 -> 1
    }
    int wave = (blockIdx.x * blockDim.x + threadIdx.x) >> 6;
    int lane = threadIdx.x & 63;
    const float* src; float* dst; int row;
    if (wave < 128)      { src = Wsrc;  dst = u; row = wave; }
    else if (wave < 256) { src = Wdst;  dst = v; row = wave - 128; }
    else if (wave < 288) { src = Wedge; dst = w; row = wave - 256; }
    else return;
    float acc = src[row * HID + lane] * avec[lane];
    for (int o = 32; o >= 1; o >>= 1) acc += __shfl_xor(acc, o);
    if (lane == 0) dst[row] = acc;
}

// ---------------- K2: p[n] = x[n].u, q[n] = x[n].v (one wave per node) ----------------
__global__ void k_pq(const float* __restrict__ x, const float* __restrict__ u,
                     const float* __restrict__ v, float* p, float* q, int N) {
    int wave = (blockIdx.x * blockDim.x + threadIdx.x) >> 6;
    int lane = threadIdx.x & 63;
    if (wave >= N) return;
    const float* xr = x + (size_t)wave * IN_DIM;
    float a0 = xr[lane], a1 = xr[lane + 64];
    float pp = a0 * u[lane] + a1 * u[lane + 64];
    float qq = a0 * v[lane] + a1 * v[lane + 64];
    for (int m = 32; m >= 1; m >>= 1) { pp += __shfl_xor(pp, m); qq += __shfl_xor(qq, m); }
    if (lane == 0) { p[wave] = pp; q[wave] = qq; }
}

// ---------------- K3: scores (8 lanes/edge, float4) ----------------
__global__ void k_escore(const float* __restrict__ ea, const int* __restrict__ ei,
                         const int* __restrict__ sflag,
                         const float* __restrict__ w, const float* __restrict__ p,
                         const float* __restrict__ q, float* scores, int E) {
    int gid = blockIdx.x * blockDim.x + threadIdx.x;
    int e = gid >> 3;
    int j = gid & 7;
    if (e >= E) return;
    float4 av = ((const float4*)ea)[(size_t)e * 8 + j];
    float4 wv = ((const float4*)w)[j];
    float val = av.x * wv.x + av.y * wv.y + av.z * wv.z + av.w * wv.w;
    val += __shfl_xor(val, 4);
    val += __shfl_xor(val, 2);
    val += __shfl_xor(val, 1);
    if (j == 0) {
        int s = sflag[0];
        int r = ei[(size_t)s * e];
        int c = ei[(size_t)s * (E + e)];
        float sc = val + p[r] + q[c];
        scores[e] = (sc > 0.f) ? sc : 0.2f * sc;
    }
}

// ---------------- K4: bin edges into col AND row sub-buckets in one sweep ----------------
__global__ void k_bin2(const int* __restrict__ ei, const int* __restrict__ sflag,
                       int* bcur_col, int* bcur_row,
                       unsigned* bbuf_col, unsigned* bbuf_row, int E) {
    int e = blockIdx.x * blockDim.x + threadIdx.x;
    if (e >= E) return;
    int s = sflag[0];
    int r = ei[(size_t)s * e];
    int c = ei[(size_t)s * (E + e)];
    int sub = blockIdx.x & (NSUB - 1);
    int pc = atomicAdd(&bcur_col[(c >> 6) * NSUB + sub], 1);
    if (pc < CAP) bbuf_col[((size_t)(c >> 6) * NSUB + sub) * CAP + pc] = (unsigned)((e << 6) | (c & 63));
    int pr = atomicAdd(&bcur_row[(r >> 6) * NSUB + sub], 1);
    if (pr < CAP) bbuf_row[((size_t)(r >> 6) * NSUB + sub) * CAP + pr] = (unsigned)((e << 6) | (r & 63));
}

// ---------------- K5: per-bucket LDS sort + softmax + attn (LDS+global) + fwd max ----------------
__global__ __launch_bounds__(512) void k_sortfwd(float* scores, const float* __restrict__ msg,
                                                 const int* __restrict__ bcur,
                                                 const unsigned* __restrict__ bbuf,
                                                 float* fwd, int N) {
    __shared__ unsigned raw[NSUB * CAP];
    __shared__ float    sc[NSUB * CAP];
    __shared__ unsigned idx[NSUB * CAP];
    __shared__ int cnt[BKT_G], cur[BKT_G], sstart[BKT_G + 1];
    __shared__ int subo[NSUB + 1];
    int b = blockIdx.x, tid = threadIdx.x;
    if (tid == 0) {
        int off = 0;
        for (int s = 0; s < NSUB; s++) {
            subo[s] = off;
            int c = bcur[b * NSUB + s]; if (c > CAP) c = CAP;
            off += c;
        }
        subo[NSUB] = off;
    }
    if (tid < BKT_G) cnt[tid] = 0;
    __syncthreads();
    int M = subo[NSUB];
    for (int s = 0; s < NSUB; s++) {
        int base = subo[s], c = subo[s + 1] - base;
        const unsigned* src = bbuf + ((size_t)b * NSUB + s) * CAP;
        for (int i = tid; i < c; i += 512) raw[base + i] = src[i];
    }
    __syncthreads();
    for (int j = tid; j < M; j += 512) {
        unsigned r = raw[j];
        sc[j] = scores[r >> 6];
        atomicAdd(&cnt[r & 63], 1);
    }
    __syncthreads();
    if (tid < BKT_G) {           // wave 0: exclusive scan of 64 counters
        int val = cnt[tid];
        int inc = val;
        for (int off = 1; off < BKT_G; off <<= 1) {
            int o = __shfl_up(inc, off);
            if (tid >= off) inc += o;
        }
        sstart[tid + 1] = inc;
        if (tid == 0) sstart[0] = 0;
        cur[tid] = inc - val;
    }
    __syncthreads();
    for (int j = tid; j < M; j += 512) {
        int c = raw[j] & 63;
        int posn = atomicAdd(&cur[c], 1);
        idx[posn] = j;
    }
    __syncthreads();
    int wave = tid >> 6, lane = tid & 63;
    for (int n = wave; n < BKT_G; n += 8) {
        int node = b * BKT_G + n;
        if (node >= N) continue;
        int a0 = sstart[n], len = sstart[n + 1] - a0;
        if (len == 0) { fwd[(size_t)node * HID + lane] = 0.f; continue; }
        float m = -FLT_MAX;
        for (int k = lane; k < len; k += 64) m = fmaxf(m, sc[idx[a0 + k]]);
        for (int o = 32; o >= 1; o >>= 1) m = fmaxf(m, __shfl_xor(m, o));
        float ssum = 0.f;
        for (int k = lane; k < len; k += 64) ssum += expf(sc[idx[a0 + k]] - m);
        for (int o = 32; o >= 1; o >>= 1) ssum += __shfl_xor(ssum, o);
        float rcp = 1.f / ssum;
        // pass 1c: attn -> LDS (wave-owned j set) and global (for sortbwd)
        for (int k = lane; k < len; k += 64) {
            unsigned j = idx[a0 + k];
            float at = expf(sc[j] - m) * rcp;
            sc[j] = at;
            scores[raw[j] >> 6] = at;
        }
        // pass 2: max over msg*attn, attn read from LDS (no exp)
        float acc = -FLT_MAX;
        int k = 0;
        for (; k + 4 <= len; k += 4) {
            unsigned j0 = idx[a0+k], j1 = idx[a0+k+1], j2 = idx[a0+k+2], j3 = idx[a0+k+3];
            float v0 = msg[(size_t)(raw[j0]>>6) * HID + lane] * sc[j0];
            float v1 = msg[(size_t)(raw[j1]>>6) * HID + lane] * sc[j1];
            float v2 = msg[(size_t)(raw[j2]>>6) * HID + lane] * sc[j2];
            float v3 = msg[(size_t)(raw[j3]>>6) * HID + lane] * sc[j3];
            acc = fmaxf(acc, fmaxf(fmaxf(v0, v1), fmaxf(v2, v3)));
        }
        for (; k < len; k++) {
            unsigned j = idx[a0 + k];
            acc = fmaxf(acc, msg[(size_t)(raw[j]>>6) * HID + lane] * sc[j]);
        }
        fwd[(size_t)node * HID + lane] = acc;
    }
}

// ---------------- K6: per-bucket LDS sort + bwd max (attn precomputed in scores) ----------------
__global__ __launch_bounds__(512) void k_sortbwd(const float* __restrict__ scores,
                                                 const float* __restrict__ msg,
                                                 const int* __restrict__ bcur,
                                                 const unsigned* __restrict__ bbuf,
                                                 float* bwd, int N) {
    __shared__ unsigned raw[NSUB * CAP];
    __shared__ float    sc[NSUB * CAP];
    __shared__ unsigned idx[NSUB * CAP];
    __shared__ int cnt[BKT_G], cur[BKT_G], sstart[BKT_G + 1];
    __shared__ int subo[NSUB + 1];
    int b = blockIdx.x, tid = threadIdx.x;
    if (tid == 0) {
        int off = 0;
        for (int s = 0; s < NSUB; s++) {
            subo[s] = off;
            int c = bcur[b * NSUB + s]; if (c > CAP) c = CAP;
            off += c;
        }
        subo[NSUB] = off;
    }
    if (tid < BKT_G) cnt[tid] = 0;
    __syncthreads();
    int M = subo[NSUB];
    for (int s = 0; s < NSUB; s++) {
        int base = subo[s], c = subo[s + 1] - base;
        const unsigned* src = bbuf + ((size_t)b * NSUB + s) * CAP;
        for (int i = tid; i < c; i += 512) raw[base + i] = src[i];
    }
    __syncthreads();
    for (int j = tid; j < M; j += 512) {
        unsigned r = raw[j];
        sc[j] = scores[r >> 6];         // attn
        atomicAdd(&cnt[r & 63], 1);
    }
    __syncthreads();
    if (tid < BKT_G) {
        int val = cnt[tid];
        int inc = val;
        for (int off = 1; off < BKT_G; off <<= 1) {
            int o = __shfl_up(inc, off);
            if (tid >= off) inc += o;
        }
        sstart[tid + 1] = inc;
        if (tid == 0) sstart[0] = 0;
        cur[tid] = inc - val;
    }
    __syncthreads();
    for (int j = tid; j < M; j += 512) {
        int c = raw[j] & 63;
        int posn = atomicAdd(&cur[c], 1);
        idx[posn] = j;
    }
    __syncthreads();
    int wave = tid >> 6, lane = tid & 63;
    for (int n = wave; n < BKT_G; n += 8) {
        int node = b * BKT_G + n;
        if (node >= N) continue;
        int a0 = sstart[n], len = sstart[n + 1] - a0;
        if (len == 0) { bwd[(size_t)node * HID + lane] = 0.f; continue; }
        float acc = -FLT_MAX;
        int k = 0;
        for (; k + 4 <= len; k += 4) {
            unsigned j0 = idx[a0+k], j1 = idx[a0+k+1], j2 = idx[a0+k+2], j3 = idx[a0+k+3];
            float v0 = msg[(size_t)(raw[j0]>>6) * HID + lane] * sc[j0];
            float v1 = msg[(size_t)(raw[j1]>>6) * HID + lane] * sc[j1];
            float v2 = msg[(size_t)(raw[j2]>>6) * HID + lane] * sc[j2];
            float v3 = msg[(size_t)(raw[j3]>>6) * HID + lane] * sc[j3];
            acc = fmaxf(acc, fmaxf(fmaxf(v0, v1), fmaxf(v2, v3)));
        }
        for (; k < len; k++) {
            unsigned j = idx[a0 + k];
            acc = fmaxf(acc, msg[(size_t)(raw[j]>>6) * HID + lane] * sc[j]);
        }
        bwd[(size_t)node * HID + lane] = acc;
    }
}

// ---------------- K7: pre1 = [fwd,bwd]@W1 + b1, fused BN stats ----------------
__global__ __launch_bounds__(256) void k_mlp1(const float* __restrict__ fwd,
                                              const float* __restrict__ bwd,
                                              const float* __restrict__ W1,
                                              const float* __restrict__ b1,
                                              float* pre1, float* gsum, float* gss, int N) {
    __shared__ float lsum[HID], lss[HID];
    int t = threadIdx.x;
    if (t < HID) { lsum[t] = 0.f; lss[t] = 0.f; }
    __syncthreads();
    int h = t & 63, lr = t >> 6;
    float bh = b1[h];
    float s = 0.f, ssq = 0.f;
    for (int n = blockIdx.x * 4 + lr; n < N; n += gridDim.x * 4) {
        const float* fr = fwd + (size_t)n * HID;
        const float* br = bwd + (size_t)n * HID;
        float acc = bh;
        for (int k = 0; k < HID; k++) acc += fr[k] * W1[k * HID + h];
        for (int k = 0; k < HID; k++) acc += br[k] * W1[(HID + k) * HID + h];
        pre1[(size_t)n * HID + h] = acc;
        s += acc; ssq += acc * acc;
    }
    atomicAdd(&lsum[h], s);
    atomicAdd(&lss[h], ssq);
    __syncthreads();
    if (t < HID) { atomicAdd(&gsum[t], lsum[t]); atomicAdd(&gss[t], lss[t]); }
}

// ---------------- K8: finalize BN -> scale/shift ----------------
__global__ void k_bnfin(const float* __restrict__ gsum, const float* __restrict__ gss,
                        const float* __restrict__ g, const float* __restrict__ b,
                        float* scale, float* shift, int N) {
    int t = threadIdx.x;
    if (t >= HID) return;
    float invN = 1.0f / (float)N;
    float mu = gsum[t] * invN;
    float var = gss[t] * invN - mu * mu;
    float rs = rsqrtf(var + 1e-5f);
    float sc = rs * g[t];
    scale[t] = sc;
    shift[t] = b[t] - mu * sc;
}

// ---------------- K9: pre2 = relu(bn1(pre1))@W2 + b2, fused BN stats ----------------
__global__ __launch_bounds__(256) void k_mlp2(const float* __restrict__ pre1,
                                              const float* __restrict__ scale1,
                                              const float* __restrict__ shift1,
                                              const float* __restrict__ W2,
                                              const float* __restrict__ b2v,
                                              float* pre2, float* gsum, float* gss, int N) {
    __shared__ float lsum[HID], lss[HID];
    int t = threadIdx.x;
    if (t < HID) { lsum[t] = 0.f; lss[t] = 0.f; }
    __syncthreads();
    int h = t & 63, lr = t >> 6;
    float bh = b2v[h];
    float s = 0.f, ssq = 0.f;
    for (int n = blockIdx.x * 4 + lr; n < N; n += gridDim.x * 4) {
        const float* pr = pre1 + (size_t)n * HID;
        float acc = bh;
        for (int k = 0; k < HID; k++) {
            float z = pr[k] * scale1[k] + shift1[k];
            z = (z > 0.f) ? z : 0.f;
            acc += z * W2[k * HID + h];
        }
        pre2[(size_t)n * HID + h] = acc;
        s += acc; ssq += acc * acc;
    }
    atomicAdd(&lsum[h], s);
    atomicAdd(&lss[h], ssq);
    __syncthreads();
    if (t < HID) { atomicAdd(&gsum[t], lsum[t]); atomicAdd(&gss[t], lss[t]); }
}

// ---------------- K10: h2 = relu(bn2(pre2)); gate = sigmoid(h2@amw+amb); f32 out ----------------
__global__ void k_out(const float* __restrict__ pre2, const float* __restrict__ scale2,
                      const float* __restrict__ shift2, const float* __restrict__ amw,
                      const float* __restrict__ amb, float* out, int N) {
    int gid = blockIdx.x * blockDim.x + threadIdx.x;
    int n = gid >> 6, h = gid & 63;
    if (n >= N) return;
    float z = pre2[(size_t)n * HID + h] * scale2[h] + shift2[h];
    float h2 = (z > 0.f) ? z : 0.f;
    out[(size_t)n * HID + h] = h2;
    float part = h2 * amw[h];
    for (int m = 32; m >= 1; m >>= 1) part += __shfl_xor(part, m);
    if (h == 0) {
        float gate = 1.0f / (1.0f + expf(-(part + amb[0])));
        out[(size_t)N * HID + n] = gate;
    }
}

extern "C" void kernel_launch(void* const* d_in, const int* in_sizes, int n_in,
                              void* d_out, int out_size, void* d_ws, size_t ws_size,
                              hipStream_t stream) {
    const float* x     = (const float*)d_in[0];
    const int*   ei    = (const int*)d_in[1];
    const float* ea    = (const float*)d_in[2];
    const float* msg   = (const float*)d_in[3];
    const float* Wsrc  = (const float*)d_in[4];
    const float* Wdst  = (const float*)d_in[5];
    const float* Wedge = (const float*)d_in[6];
    const float* avec  = (const float*)d_in[7];
    const float* W1    = (const float*)d_in[8];
    const float* b1    = (const float*)d_in[9];
    const float* g1    = (const float*)d_in[10];
    const float* bb1   = (const float*)d_in[11];
    const float* W2    = (const float*)d_in[12];
    const float* b2    = (const float*)d_in[13];
    const float* g2    = (const float*)d_in[14];
    const float* bb2   = (const float*)d_in[15];
    const float* amw   = (const float*)d_in[16];
    const float* amb   = (const float*)d_in[17];
    float* out = (float*)d_out;

    const int N = in_sizes[0] / IN_DIM;   // 50000
    const int E = in_sizes[1] / 2;        // 800000
    const int NH = N * HID;
    const int nbkt = (N + BKT_G - 1) / BKT_G;   // 782

    // ---- workspace ----
    float* ws = (float*)d_ws;
    float* gsum1  = ws;
    float* gss1   = ws + 64;
    float* gsum2  = ws + 128;
    float* gss2   = ws + 192;
    float* scale1 = ws + 256;
    float* shift1 = ws + 320;
    float* scale2 = ws + 384;
    float* shift2 = ws + 448;
    int*   sflag  = (int*)(ws + 512);
    float* u      = ws + 576;
    float* v      = ws + 704;
    float* w      = ws + 832;   // 16B-aligned
    float* T        = ws + 1024;
    float* p        = T;                               // N
    float* q        = p + N;                           // N
    float* scores   = q + N;                           // E (attn after sortfwd)
    int*   bcur_col = (int*)(scores + E);              // nbkt*NSUB
    int*   bcur_row = bcur_col + nbkt * NSUB;          // nbkt*NSUB
    unsigned* bbuf_col = (unsigned*)(bcur_row + nbkt * NSUB);   // nbkt*NSUB*CAP
    unsigned* bbuf_row = bbuf_col + (size_t)nbkt * NSUB * CAP;  // nbkt*NSUB*CAP
    size_t T_words  = 2 * (size_t)N + E + 2 * (size_t)nbkt * NSUB
                    + 2 * (size_t)nbkt * NSUB * CAP;
    size_t T_sz     = (T_words < (size_t)NH) ? (size_t)NH : T_words;
    float* fwd  = ws + 1024 + T_sz;                    // NH
    float* bwd  = fwd + (size_t)NH;                    // NH
    float* pre1 = T;                                   // overlay transients (dead)
    float* pre2 = fwd;                                 // overlay fwd (dead after mlp1)

    (void)hipMemsetAsync(bcur_col, 0, (size_t)2 * nbkt * NSUB * sizeof(int), stream);
    (void)hipMemsetAsync(ws, 0, 512 * sizeof(float), stream);
    hipLaunchKernelGGL(k_uvw, dim3(72), dim3(256), 0, stream,
                       Wsrc, Wdst, Wedge, avec, ei, sflag, u, v, w);
    hipLaunchKernelGGL(k_pq, dim3((N * 64 + 255) / 256), dim3(256), 0, stream,
                       x, u, v, p, q, N);
    hipLaunchKernelGGL(k_escore, dim3((E * 8 + 255) / 256), dim3(256), 0, stream,
                       ea, ei, sflag, w, p, q, scores, E);
    hipLaunchKernelGGL(k_bin2, dim3((E + 255) / 256), dim3(256), 0, stream,
                       ei, sflag, bcur_col, bcur_row, bbuf_col, bbuf_row, E);
    hipLaunchKernelGGL(k_sortfwd, dim3(nbkt), dim3(512), 0, stream,
                       scores, msg, bcur_col, bbuf_col, fwd, N);
    hipLaunchKernelGGL(k_sortbwd, dim3(nbkt), dim3(512), 0, stream,
                       scores, msg, bcur_row, bbuf_row, bwd, N);
    hipLaunchKernelGGL(k_mlp1, dim3(1024), dim3(256), 0, stream,
                       fwd, bwd, W1, b1, pre1, gsum1, gss1, N);
    hipLaunchKernelGGL(k_bnfin, dim3(1), dim3(64), 0, stream,
                       gsum1, gss1, g1, bb1, scale1, shift1, N);
    hipLaunchKernelGGL(k_mlp2, dim3(1024), dim3(256), 0, stream,
                       pre1, scale1, shift1, W2, b2, pre2, gsum2, gss2, N);
    hipLaunchKernelGGL(k_bnfin, dim3(1), dim3(64), 0, stream,
                       gsum2, gss2, g2, bb2, scale2, shift2, N);
    hipLaunchKernelGGL(k_out, dim3((N * 64 + 255) / 256), dim3(256), 0, stream,
                       pre2, scale2, shift2, amw, amb, out, N);
}

// Round 13
// 417.677 us; speedup vs baseline: 1.8360x; 1.0290x over previous
//
#include <hip/hip_runtime.h>
#include <hip/hip_bf16.h>
#include <float.h>

#define IN_DIM 128
#define EDGE_DIM 32
#define HID 64
#define BKT_G 64          // nodes per bucket
#define NSUB 8            // sub-buckets (XCD-affinity via blockIdx&7)
#define CAP 384           // per-sub-bucket capacity

// ---------------- K1: u,v,w projections + edge_index stride detect ----------------
__global__ void k_uvw(const float* __restrict__ Wsrc, const float* __restrict__ Wdst,
                      const float* __restrict__ Wedge, const float* __restrict__ avec,
                      const int* __restrict__ ei32, int* sflag,
                      float* u, float* v, float* w) {
    if (blockIdx.x == 0 && threadIdx.x == 0) {
        int odd_or = ei32[1] | ei32[3] | ei32[5] | ei32[7] | ei32[9] | ei32[11];
        sflag[0] = (odd_or == 0) ? 2 : 1;   // int64 -> 2 words/elem, int32 -> 1
    }
    int wave = (blockIdx.x * blockDim.x + threadIdx.x) >> 6;
    int lane = threadIdx.x & 63;
    const float* src; float* dst; int row;
    if (wave < 128)      { src = Wsrc;  dst = u; row = wave; }
    else if (wave < 256) { src = Wdst;  dst = v; row = wave - 128; }
    else if (wave < 288) { src = Wedge; dst = w; row = wave - 256; }
    else return;
    float acc = src[row * HID + lane] * avec[lane];
    for (int o = 32; o >= 1; o >>= 1) acc += __shfl_xor(acc, o);
    if (lane == 0) dst[row] = acc;
}

// ---------------- K2: p[n] = x[n].u, q[n] = x[n].v (one wave per node) ----------------
__global__ void k_pq(const float* __restrict__ x, const float* __restrict__ u,
                     const float* __restrict__ v, float* p, float* q, int N) {
    int wave = (blockIdx.x * blockDim.x + threadIdx.x) >> 6;
    int lane = threadIdx.x & 63;
    if (wave >= N) return;
    const float* xr = x + (size_t)wave * IN_DIM;
    float a0 = xr[lane], a1 = xr[lane + 64];
    float pp = a0 * u[lane] + a1 * u[lane + 64];
    float qq = a0 * v[lane] + a1 * v[lane + 64];
    for (int m = 32; m >= 1; m >>= 1) { pp += __shfl_xor(pp, m); qq += __shfl_xor(qq, m); }
    if (lane == 0) { p[wave] = pp; q[wave] = qq; }
}

// ---------------- K3: scores, thread-per-edge via LDS tile; fused binning ----------------
__global__ __launch_bounds__(256) void k_escore(const float* __restrict__ ea,
                                                const int* __restrict__ ei,
                                                const int* __restrict__ sflag,
                                                const float* __restrict__ w,
                                                const float* __restrict__ p,
                                                const float* __restrict__ q,
                                                float* scores,
                                                int* bcur_col, int* bcur_row,
                                                unsigned* bbuf_col, unsigned* bbuf_row,
                                                int E) {
    __shared__ float sea[256 * 33];   // padded rows: read bank = (tid+j)%32, conflict-free
    __shared__ float sw[EDGE_DIM];
    int tid = threadIdx.x;
    int e0 = blockIdx.x * 256;
    if (tid < EDGE_DIM) sw[tid] = w[tid];
    const float4* ea4 = (const float4*)ea;
    for (int i = tid; i < 2048; i += 256) {          // 256 edges x 8 float4
        int el = i >> 3, j = i & 7;
        int e = e0 + el;
        float4 vv = (e < E) ? ea4[(size_t)e * 8 + j] : make_float4(0.f, 0.f, 0.f, 0.f);
        int base = el * 33 + j * 4;
        sea[base] = vv.x; sea[base + 1] = vv.y; sea[base + 2] = vv.z; sea[base + 3] = vv.w;
    }
    __syncthreads();
    int e = e0 + tid;
    if (e >= E) return;
    float s = 0.f;
#pragma unroll
    for (int j = 0; j < EDGE_DIM; j++) s += sea[tid * 33 + j] * sw[j];
    int st = sflag[0];
    int r = ei[(size_t)st * e];
    int c = ei[(size_t)st * (E + e)];
    float sc = s + p[r] + q[c];
    scores[e] = (sc > 0.f) ? sc : 0.2f * sc;
    // fused binning (same r,c already in registers)
    int sub = blockIdx.x & (NSUB - 1);
    int pc = atomicAdd(&bcur_col[(c >> 6) * NSUB + sub], 1);
    if (pc < CAP) bbuf_col[((size_t)(c >> 6) * NSUB + sub) * CAP + pc] = (unsigned)((e << 6) | (c & 63));
    int pr = atomicAdd(&bcur_row[(r >> 6) * NSUB + sub], 1);
    if (pr < CAP) bbuf_row[((size_t)(r >> 6) * NSUB + sub) * CAP + pr] = (unsigned)((e << 6) | (r & 63));
}

// ---------------- K5: per-bucket sorted-LDS softmax + attn + fwd max ----------------
__global__ __launch_bounds__(512) void k_sortfwd(float* scores, const float* __restrict__ msg,
                                                 const int* __restrict__ bcur,
                                                 const unsigned* __restrict__ bbuf,
                                                 float* fwd, int N) {
    __shared__ unsigned raw[NSUB * CAP];
    __shared__ unsigned srt[NSUB * CAP];   // bucket entries sorted by node
    __shared__ float    ssc[NSUB * CAP];   // matching score -> attn
    __shared__ int cnt[BKT_G], cur[BKT_G], sstart[BKT_G + 1];
    __shared__ int subo[NSUB + 1];
    int b = blockIdx.x, tid = threadIdx.x;
    if (tid == 0) {
        int off = 0;
        for (int s = 0; s < NSUB; s++) {
            subo[s] = off;
            int c = bcur[b * NSUB + s]; if (c > CAP) c = CAP;
            off += c;
        }
        subo[NSUB] = off;
    }
    if (tid < BKT_G) cnt[tid] = 0;
    __syncthreads();
    int M = subo[NSUB];
    for (int s = 0; s < NSUB; s++) {       // load + histogram in one pass
        int base = subo[s], c = subo[s + 1] - base;
        const unsigned* src = bbuf + ((size_t)b * NSUB + s) * CAP;
        for (int i = tid; i < c; i += 512) {
            unsigned v = src[i];
            raw[base + i] = v;
            atomicAdd(&cnt[v & 63], 1);
        }
    }
    __syncthreads();
    if (tid < BKT_G) {                     // wave 0: exclusive scan of 64 counters
        int val = cnt[tid];
        int inc = val;
        for (int off = 1; off < BKT_G; off <<= 1) {
            int o = __shfl_up(inc, off);
            if (tid >= off) inc += o;
        }
        sstart[tid + 1] = inc;
        if (tid == 0) sstart[0] = 0;
        cur[tid] = inc - val;
    }
    __syncthreads();
    for (int j = tid; j < M; j += 512) {   // scatter entries into sorted order
        unsigned v = raw[j];
        int posn = atomicAdd(&cur[v & 63], 1);
        srt[posn] = v;
    }
    __syncthreads();
    for (int i = tid; i < M; i += 512) ssc[i] = scores[srt[i] >> 6];
    __syncthreads();
    int wave = tid >> 6, lane = tid & 63;
    for (int n = wave; n < BKT_G; n += 8) {
        int node = b * BKT_G + n;
        if (node >= N) continue;
        int a0 = sstart[n], len = sstart[n + 1] - a0;
        if (len == 0) { fwd[(size_t)node * HID + lane] = 0.f; continue; }
        float m = -FLT_MAX;
        for (int k = lane; k < len; k += 64) m = fmaxf(m, ssc[a0 + k]);
        for (int o = 32; o >= 1; o >>= 1) m = fmaxf(m, __shfl_xor(m, o));
        float ssum = 0.f;
        for (int k = lane; k < len; k += 64) ssum += expf(ssc[a0 + k] - m);
        for (int o = 32; o >= 1; o >>= 1) ssum += __shfl_xor(ssum, o);
        float rcp = 1.f / ssum;
        for (int k = lane; k < len; k += 64) {   // attn -> LDS + global (wave-owned range)
            int i = a0 + k;
            float at = expf(ssc[i] - m) * rcp;
            ssc[i] = at;
            scores[srt[i] >> 6] = at;
        }
        asm volatile("s_waitcnt lgkmcnt(0)" ::: "memory");
        float acc = -FLT_MAX;
        int k = 0;
        for (; k + 8 <= len; k += 8) {
            float vv[8];
#pragma unroll
            for (int u8 = 0; u8 < 8; u8++) {
                int i = a0 + k + u8;
                vv[u8] = msg[(size_t)(srt[i] >> 6) * HID + lane] * ssc[i];
            }
#pragma unroll
            for (int u8 = 0; u8 < 8; u8++) acc = fmaxf(acc, vv[u8]);
        }
        for (; k < len; k++) {
            int i = a0 + k;
            acc = fmaxf(acc, msg[(size_t)(srt[i] >> 6) * HID + lane] * ssc[i]);
        }
        fwd[(size_t)node * HID + lane] = acc;
    }
}

// ---------------- K6: per-bucket sorted-LDS bwd max (attn precomputed) ----------------
__global__ __launch_bounds__(512) void k_sortbwd(const float* __restrict__ scores,
                                                 const float* __restrict__ msg,
                                                 const int* __restrict__ bcur,
                                                 const unsigned* __restrict__ bbuf,
                                                 float* bwd, int N) {
    __shared__ unsigned raw[NSUB * CAP];
    __shared__ unsigned srt[NSUB * CAP];
    __shared__ float    ssc[NSUB * CAP];
    __shared__ int cnt[BKT_G], cur[BKT_G], sstart[BKT_G + 1];
    __shared__ int subo[NSUB + 1];
    int b = blockIdx.x, tid = threadIdx.x;
    if (tid == 0) {
        int off = 0;
        for (int s = 0; s < NSUB; s++) {
            subo[s] = off;
            int c = bcur[b * NSUB + s]; if (c > CAP) c = CAP;
            off += c;
        }
        subo[NSUB] = off;
    }
    if (tid < BKT_G) cnt[tid] = 0;
    __syncthreads();
    int M = subo[NSUB];
    for (int s = 0; s < NSUB; s++) {
        int base = subo[s], c = subo[s + 1] - base;
        const unsigned* src = bbuf + ((size_t)b * NSUB + s) * CAP;
        for (int i = tid; i < c; i += 512) {
            unsigned v = src[i];
            raw[base + i] = v;
            atomicAdd(&cnt[v & 63], 1);
        }
    }
    __syncthreads();
    if (tid < BKT_G) {
        int val = cnt[tid];
        int inc = val;
        for (int off = 1; off < BKT_G; off <<= 1) {
            int o = __shfl_up(inc, off);
            if (tid >= off) inc += o;
        }
        sstart[tid + 1] = inc;
        if (tid == 0) sstart[0] = 0;
        cur[tid] = inc - val;
    }
    __syncthreads();
    for (int j = tid; j < M; j += 512) {
        unsigned v = raw[j];
        int posn = atomicAdd(&cur[v & 63], 1);
        srt[posn] = v;
    }
    __syncthreads();
    for (int i = tid; i < M; i += 512) ssc[i] = scores[srt[i] >> 6];   // attn
    __syncthreads();
    int wave = tid >> 6, lane = tid & 63;
    for (int n = wave; n < BKT_G; n += 8) {
        int node = b * BKT_G + n;
        if (node >= N) continue;
        int a0 = sstart[n], len = sstart[n + 1] - a0;
        if (len == 0) { bwd[(size_t)node * HID + lane] = 0.f; continue; }
        float acc = -FLT_MAX;
        int k = 0;
        for (; k + 8 <= len; k += 8) {
            float vv[8];
#pragma unroll
            for (int u8 = 0; u8 < 8; u8++) {
                int i = a0 + k + u8;
                vv[u8] = msg[(size_t)(srt[i] >> 6) * HID + lane] * ssc[i];
            }
#pragma unroll
            for (int u8 = 0; u8 < 8; u8++) acc = fmaxf(acc, vv[u8]);
        }
        for (; k < len; k++) {
            int i = a0 + k;
            acc = fmaxf(acc, msg[(size_t)(srt[i] >> 6) * HID + lane] * ssc[i]);
        }
        bwd[(size_t)node * HID + lane] = acc;
    }
}

// ---------------- K7: pre1 = [fwd,bwd]@W1 + b1, fused BN stats ----------------
__global__ __launch_bounds__(256) void k_mlp1(const float* __restrict__ fwd,
                                              const float* __restrict__ bwd,
                                              const float* __restrict__ W1,
                                              const float* __restrict__ b1,
                                              float* pre1, float* gsum, float* gss, int N) {
    __shared__ float lsum[HID], lss[HID];
    int t = threadIdx.x;
    if (t < HID) { lsum[t] = 0.f; lss[t] = 0.f; }
    __syncthreads();
    int h = t & 63, lr = t >> 6;
    float bh = b1[h];
    float s = 0.f, ssq = 0.f;
    for (int n = blockIdx.x * 4 + lr; n < N; n += gridDim.x * 4) {
        const float* fr = fwd + (size_t)n * HID;
        const float* br = bwd + (size_t)n * HID;
        float acc = bh;
        for (int k = 0; k < HID; k++) acc += fr[k] * W1[k * HID + h];
        for (int k = 0; k < HID; k++) acc += br[k] * W1[(HID + k) * HID + h];
        pre1[(size_t)n * HID + h] = acc;
        s += acc; ssq += acc * acc;
    }
    atomicAdd(&lsum[h], s);
    atomicAdd(&lss[h], ssq);
    __syncthreads();
    if (t < HID) { atomicAdd(&gsum[t], lsum[t]); atomicAdd(&gss[t], lss[t]); }
}

// ---------------- K8: finalize BN -> scale/shift ----------------
__global__ void k_bnfin(const float* __restrict__ gsum, const float* __restrict__ gss,
                        const float* __restrict__ g, const float* __restrict__ b,
                        float* scale, float* shift, int N) {
    int t = threadIdx.x;
    if (t >= HID) return;
    float invN = 1.0f / (float)N;
    float mu = gsum[t] * invN;
    float var = gss[t] * invN - mu * mu;
    float rs = rsqrtf(var + 1e-5f);
    float sc = rs * g[t];
    scale[t] = sc;
    shift[t] = b[t] - mu * sc;
}

// ---------------- K9: pre2 = relu(bn1(pre1))@W2 + b2, fused BN stats ----------------
__global__ __launch_bounds__(256) void k_mlp2(const float* __restrict__ pre1,
                                              const float* __restrict__ scale1,
                                              const float* __restrict__ shift1,
                                              const float* __restrict__ W2,
                                              const float* __restrict__ b2v,
                                              float* pre2, float* gsum, float* gss, int N) {
    __shared__ float lsum[HID], lss[HID];
    int t = threadIdx.x;
    if (t < HID) { lsum[t] = 0.f; lss[t] = 0.f; }
    __syncthreads();
    int h = t & 63, lr = t >> 6;
    float bh = b2v[h];
    float s = 0.f, ssq = 0.f;
    for (int n = blockIdx.x * 4 + lr; n < N; n += gridDim.x * 4) {
        const float* pr = pre1 + (size_t)n * HID;
        float acc = bh;
        for (int k = 0; k < HID; k++) {
            float z = pr[k] * scale1[k] + shift1[k];
            z = (z > 0.f) ? z : 0.f;
            acc += z * W2[k * HID + h];
        }
        pre2[(size_t)n * HID + h] = acc;
        s += acc; ssq += acc * acc;
    }
    atomicAdd(&lsum[h], s);
    atomicAdd(&lss[h], ssq);
    __syncthreads();
    if (t < HID) { atomicAdd(&gsum[t], lsum[t]); atomicAdd(&gss[t], lss[t]); }
}

// ---------------- K10: h2 = relu(bn2(pre2)); gate = sigmoid(h2@amw+amb); f32 out ----------------
__global__ void k_out(const float* __restrict__ pre2, const float* __restrict__ scale2,
                      const float* __restrict__ shift2, const float* __restrict__ amw,
                      const float* __restrict__ amb, float* out, int N) {
    int gid = blockIdx.x * blockDim.x + threadIdx.x;
    int n = gid >> 6, h = gid & 63;
    if (n >= N) return;
    float z = pre2[(size_t)n * HID + h] * scale2[h] + shift2[h];
    float h2 = (z > 0.f) ? z : 0.f;
    out[(size_t)n * HID + h] = h2;
    float part = h2 * amw[h];
    for (int m = 32; m >= 1; m >>= 1) part += __shfl_xor(part, m);
    if (h == 0) {
        float gate = 1.0f / (1.0f + expf(-(part + amb[0])));
        out[(size_t)N * HID + n] = gate;
    }
}

extern "C" void kernel_launch(void* const* d_in, const int* in_sizes, int n_in,
                              void* d_out, int out_size, void* d_ws, size_t ws_size,
                              hipStream_t stream) {
    const float* x     = (const float*)d_in[0];
    const int*   ei    = (const int*)d_in[1];
    const float* ea    = (const float*)d_in[2];
    const float* msg   = (const float*)d_in[3];
    const float* Wsrc  = (const float*)d_in[4];
    const float* Wdst  = (const float*)d_in[5];
    const float* Wedge = (const float*)d_in[6];
    const float* avec  = (const float*)d_in[7];
    const float* W1    = (const float*)d_in[8];
    const float* b1    = (const float*)d_in[9];
    const float* g1    = (const float*)d_in[10];
    const float* bb1   = (const float*)d_in[11];
    const float* W2    = (const float*)d_in[12];
    const float* b2    = (const float*)d_in[13];
    const float* g2    = (const float*)d_in[14];
    const float* bb2   = (const float*)d_in[15];
    const float* amw   = (const float*)d_in[16];
    const float* amb   = (const float*)d_in[17];
    float* out = (float*)d_out;

    const int N = in_sizes[0] / IN_DIM;   // 50000
    const int E = in_sizes[1] / 2;        // 800000
    const int NH = N * HID;
    const int nbkt = (N + BKT_G - 1) / BKT_G;   // 782

    // ---- workspace ----
    float* ws = (float*)d_ws;
    float* gsum1  = ws;
    float* gss1   = ws + 64;
    float* gsum2  = ws + 128;
    float* gss2   = ws + 192;
    float* scale1 = ws + 256;
    float* shift1 = ws + 320;
    float* scale2 = ws + 384;
    float* shift2 = ws + 448;
    int*   sflag  = (int*)(ws + 512);
    float* u      = ws + 576;
    float* v      = ws + 704;
    float* w      = ws + 832;   // 16B-aligned
    float* T        = ws + 1024;
    float* p        = T;                               // N
    float* q        = p + N;                           // N
    float* scores   = q + N;                           // E (attn after sortfwd)
    int*   bcur_col = (int*)(scores + E);              // nbkt*NSUB
    int*   bcur_row = bcur_col + nbkt * NSUB;          // nbkt*NSUB
    unsigned* bbuf_col = (unsigned*)(bcur_row + nbkt * NSUB);   // nbkt*NSUB*CAP
    unsigned* bbuf_row = bbuf_col + (size_t)nbkt * NSUB * CAP;  // nbkt*NSUB*CAP
    size_t T_words  = 2 * (size_t)N + E + 2 * (size_t)nbkt * NSUB
                    + 2 * (size_t)nbkt * NSUB * CAP;
    size_t T_sz     = (T_words < (size_t)NH) ? (size_t)NH : T_words;
    float* fwd  = ws + 1024 + T_sz;                    // NH
    float* bwd  = fwd + (size_t)NH;                    // NH
    float* pre1 = T;                                   // overlay transients (dead)
    float* pre2 = fwd;                                 // overlay fwd (dead after mlp1)

    (void)hipMemsetAsync(bcur_col, 0, (size_t)2 * nbkt * NSUB * sizeof(int), stream);
    (void)hipMemsetAsync(ws, 0, 512 * sizeof(float), stream);
    hipLaunchKernelGGL(k_uvw, dim3(72), dim3(256), 0, stream,
                       Wsrc, Wdst, Wedge, avec, ei, sflag, u, v, w);
    hipLaunchKernelGGL(k_pq, dim3((N * 64 + 255) / 256), dim3(256), 0, stream,
                       x, u, v, p, q, N);
    hipLaunchKernelGGL(k_escore, dim3((E + 255) / 256), dim3(256), 0, stream,
                       ea, ei, sflag, w, p, q, scores,
                       bcur_col, bcur_row, bbuf_col, bbuf_row, E);
    hipLaunchKernelGGL(k_sortfwd, dim3(nbkt), dim3(512), 0, stream,
                       scores, msg, bcur_col, bbuf_col, fwd, N);
    hipLaunchKernelGGL(k_sortbwd, dim3(nbkt), dim3(512), 0, stream,
                       scores, msg, bcur_row, bbuf_row, bwd, N);
    hipLaunchKernelGGL(k_mlp1, dim3(1024), dim3(256), 0, stream,
                       fwd, bwd, W1, b1, pre1, gsum1, gss1, N);
    hipLaunchKernelGGL(k_bnfin, dim3(1), dim3(64), 0, stream,
                       gsum1, gss1, g1, bb1, scale1, shift1, N);
    hipLaunchKernelGGL(k_mlp2, dim3(1024), dim3(256), 0, stream,
                       pre1, scale1, shift1, W2, b2, pre2, gsum2, gss2, N);
    hipLaunchKernelGGL(k_bnfin, dim3(1), dim3(64), 0, stream,
                       gsum2, gss2, g2, bb2, scale2, shift2, N);
    hipLaunchKernelGGL(k_out, dim3((N * 64 + 255) / 256), dim3(256), 0, stream,
                       pre2, scale2, shift2, amw, amb, out, N);
}